// Round 17
// baseline (11973.913 us; speedup 1.0000x reference)
//
#include <hip/hip_runtime.h>

typedef unsigned short u16;
typedef unsigned int   u32;

// B=64, T=12, N=1024, DIN=2, HID=64, ED=10, K=2
// f32 recurrence. Two-layer pipeline (layer1(t) || layer0(t+1)).
// R17: gate/upd = ONE block per node (64 batches) -> weight L2 traffic and
// combine FLOPs halved. LDS 73.7KB -> 2 blocks/CU.

__device__ __forceinline__ float bf2f(u16 u){ return __uint_as_float(((u32)u)<<16); }
__device__ __forceinline__ u16 f2bf(float f){
  u32 u = __float_as_uint(f);
  return (u16)((u + 0x7fffu + ((u>>16)&1u)) >> 16);
}

// ---------------------------------------------------------------------------
// softmax(relu(E E^T), axis=1) -> col-major At, diagA.  grid 1024, block 256
__global__ __launch_bounds__(256) void k_A2(const float* __restrict__ E,
    float* __restrict__ At, float* __restrict__ diagA)
{
  __shared__ float EL[10][1024];
  __shared__ float row[1024];
  __shared__ float red[4];
  int n = blockIdx.x, tid = threadIdx.x;
  for (int idx=tid; idx<10240; idx+=256)
    EL[idx>>10][idx&1023] = E[(idx&1023)*10 + (idx>>10)];
  __syncthreads();
  float en[10];
#pragma unroll
  for (int e=0;e<10;++e) en[e] = EL[e][n];
  float lmax = -1e30f;
#pragma unroll
  for (int j=0;j<4;++j){
    int m = tid*4 + j;
    float d = 0.f;
#pragma unroll
    for (int e=0;e<10;++e) d = fmaf(en[e], EL[e][m], d);
    d = fmaxf(d, 0.f);
    row[m] = d; lmax = fmaxf(lmax, d);
  }
#pragma unroll
  for (int o=32;o>0;o>>=1) lmax = fmaxf(lmax, __shfl_xor(lmax, o));
  if ((tid&63)==0) red[tid>>6] = lmax;
  __syncthreads();
  float mx = fmaxf(fmaxf(red[0],red[1]), fmaxf(red[2],red[3]));
  __syncthreads();
  float lsum = 0.f;
#pragma unroll
  for (int j=0;j<4;++j){
    int m = tid*4 + j;
    float ex = expf(row[m] - mx);
    row[m] = ex; lsum += ex;
  }
#pragma unroll
  for (int o=32;o>0;o>>=1) lsum += __shfl_xor(lsum, o);
  if ((tid&63)==0) red[tid>>6] = lsum;
  __syncthreads();
  float inv = 1.f/(red[0]+red[1]+red[2]+red[3]);
#pragma unroll
  for (int j=0;j<4;++j){
    int m = tid*4 + j;
    float v = row[m]*inv;
    At[(size_t)m*1024 + n] = v;
    if (m == n) diagA[n] = v;
  }
}

// ---------------------------------------------------------------------------
__global__ __launch_bounds__(64) void k_b3eff(
    const float* __restrict__ b2, const float* __restrict__ W3,
    const float* __restrict__ b3, float* __restrict__ b3eff)
{
  int o = threadIdx.x;
  if (o < 12){
    float a = b3[o];
    for (int i=0;i<12;++i)
      a += b2[i] * (W3[(o*12+i)*2] + W3[(o*12+i)*2+1]);
    b3eff[o] = a;
  }
}

// ---------------------------------------------------------------------------
__global__ __launch_bounds__(256) void k_Vpre(const float* __restrict__ W1,
    const float* __restrict__ W2, float* __restrict__ V)
{
  int idx = blockIdx.x*256 + threadIdx.x;
  if (idx >= 9216) return;
  int c = idx & 63, r = idx >> 6;
  int j = r % 12, i = r / 12;
  float a = 0.f;
  for (int o=0;o<64;++o)
    a = fmaf(W2[(i*12+j)*64+o], W1[o*64+c], a);
  V[idx] = a;
}

// ---------------------------------------------------------------------------
__global__ __launch_bounds__(256) void k_Gpre(const float* __restrict__ Wc,
    const float* __restrict__ W2, u16* __restrict__ G)
{
  int idx = blockIdx.x*256 + threadIdx.x;
  int u = idx & 127, r = idx >> 7;
  int ip = r % 12, i = r / 12;
  float a = 0.f;
  int wlo = u>64 ? u-64 : 0;
  int whi = u<63 ? u : 63;
  for (int j=0;j<12;++j){
    const float* w2r = W2 + (i*12+j)*64;
    const float* wcr = Wc + (j*12+ip)*65;
    for (int w=wlo; w<=whi; ++w)
      a = fmaf(w2r[w], wcr[u-w], a);
  }
  G[idx] = f2bf(a);
}

// ---------------------------------------------------------------------------
__global__ __launch_bounds__(256) void k_combF(const float* __restrict__ Wp,
    const float* __restrict__ E, float* __restrict__ out, int plane)
{
  int n = blockIdx.x;
  int j = blockIdx.y*256 + threadIdx.x;
  if (j >= plane) return;
  float a = 0.f;
#pragma unroll
  for (int e=0;e<10;++e) a = fmaf(E[n*10+e], Wp[(size_t)e*plane + j], a);
  out[(size_t)n*plane + j] = a;
}

// ---------------------------------------------------------------------------
// gemm9: Y[s][n][c] = sum_m At[m][n]*X[s][m][c]  (f32)
// 128n x 128col tile (2 slabs/block), chunk 16, dbuf, 8x8 acc. XCD-sticky.
// grid (8, 32, NZ).
__global__ __launch_bounds__(256) void gemm9(const float* __restrict__ At,
    const float* __restrict__ X0, float* __restrict__ Y0,
    const float* __restrict__ X1, float* __restrict__ Y1)
{
  int flat = blockIdx.x + (blockIdx.y<<3) + (blockIdx.z<<8);
  int xt = flat & 7;
  int ys = (flat>>3) & 31;
  int zs = flat >> 8;
  const float* X = zs ? X1 : X0;
  float*       Y = zs ? Y1 : Y0;
  int n0 = xt * 128;
  long baseA = (long)(2*ys) * 65536;
  long baseB = baseA + 65536;
  __shared__ float Al[2][16*128];
  __shared__ float Xl[2][16*128];
  int tid = threadIdx.x;
  int tx = tid & 15, ty = tid >> 4;
  int ka = tid >> 5,  na = (tid & 31)*4;
  int cx = tid & 31;
  long xoff = (cx < 16) ? (baseA + (long)cx*4) : (baseB + (long)(cx-16)*4);

  float accA[8][4], accB[8][4];
#pragma unroll
  for (int r=0;r<8;++r)
#pragma unroll
    for (int c=0;c<4;++c){ accA[r][c]=0.f; accB[r][c]=0.f; }

  float4 ra0 = *(const float4*)(At + (size_t)ka*1024 + n0 + na);
  float4 ra1 = *(const float4*)(At + (size_t)(ka+8)*1024 + n0 + na);
  float4 rx0 = *(const float4*)(X + xoff + (long)ka*64);
  float4 rx1 = *(const float4*)(X + xoff + (long)(ka+8)*64);

  for (int m0=0; m0<1024; m0+=16){
    int cur = (m0>>4)&1;
    *(float4*)(Al[cur] + tid*4)       = ra0;
    *(float4*)(Al[cur] + (tid+256)*4) = ra1;
    *(float4*)(Xl[cur] + tid*4)       = rx0;
    *(float4*)(Xl[cur] + (tid+256)*4) = rx1;
    __syncthreads();
    if (m0+16 < 1024){
      int m1 = m0+16;
      ra0 = *(const float4*)(At + (size_t)(m1+ka)*1024 + n0 + na);
      ra1 = *(const float4*)(At + (size_t)(m1+ka+8)*1024 + n0 + na);
      rx0 = *(const float4*)(X + xoff + (long)(m1+ka)*64);
      rx1 = *(const float4*)(X + xoff + (long)(m1+ka+8)*64);
    }
#pragma unroll
    for (int kk=0;kk<16;++kk){
      float4 a0 = *(const float4*)(Al[cur] + kk*128 + ty*4);
      float4 a1 = *(const float4*)(Al[cur] + kk*128 + 64 + ty*4);
      float4 x0 = *(const float4*)(Xl[cur] + kk*128 + tx*4);
      float4 x1 = *(const float4*)(Xl[cur] + kk*128 + 64 + tx*4);
      float av[8] = {a0.x,a0.y,a0.z,a0.w,a1.x,a1.y,a1.z,a1.w};
      float xa[4] = {x0.x,x0.y,x0.z,x0.w};
      float xb[4] = {x1.x,x1.y,x1.z,x1.w};
#pragma unroll
      for (int r=0;r<8;++r)
#pragma unroll
        for (int c=0;c<4;++c){
          accA[r][c] = fmaf(av[r], xa[c], accA[r][c]);
          accB[r][c] = fmaf(av[r], xb[c], accB[r][c]);
        }
    }
  }
#pragma unroll
  for (int r=0;r<8;++r){
    int row = n0 + (r>>2)*64 + ty*4 + (r&3);
    float4 vA; vA.x=accA[r][0]; vA.y=accA[r][1]; vA.z=accA[r][2]; vA.w=accA[r][3];
    float4 vB; vB.x=accB[r][0]; vB.y=accB[r][1]; vB.z=accB[r][2]; vB.w=accB[r][3];
    *(float4*)&Y[baseA + (long)row*64 + tx*4] = vA;
    *(float4*)&Y[baseB + (long)row*64 + tx*4] = vB;
  }
}

// ---------------------------------------------------------------------------
// gemm2x (fused x-gather, one-shot): Ax0T[n][q] = sum_m At[m][n]*x[q>>1,m,q&1]
__global__ __launch_bounds__(256) void gemm2x(const float* __restrict__ At,
    const float* __restrict__ x, float* __restrict__ Y)
{
  __shared__ float Ats[64][65];
  __shared__ float Xs[64][65];
  int n0 = blockIdx.x*64;
  int q0 = blockIdx.y*64;
  int tid = threadIdx.x, c = tid & 63, rq = tid >> 6;
  float acc[16];
#pragma unroll
  for (int j=0;j<16;++j) acc[j]=0.f;
  for (int m0=0; m0<1024; m0+=64){
#pragma unroll
    for (int j=0;j<16;++j){
      int idx = tid + j*256;
      int k = idx>>6, r = idx&63;
      Ats[k][r] = At[(size_t)(m0+k)*1024 + n0 + r];
      int qg = q0 + r;
      Xs[k][r] = x[(size_t)(qg>>1)*2048 + (size_t)(m0+k)*2 + (qg&1)];
    }
    __syncthreads();
    for (int k=0;k<64;++k){
      float xv = Xs[k][c];
#pragma unroll
      for (int j=0;j<16;++j) acc[j] = fmaf(Ats[k][rq+4*j], xv, acc[j]);
    }
    __syncthreads();
  }
#pragma unroll
  for (int j=0;j<16;++j)
    Y[(size_t)(n0+rq+4*j)*1536 + q0 + c] = acc[j];
}

// ---------------------------------------------------------------------------
// Gate body, 64 batches/block. Wpre != nullptr -> copy precombined; else combine.
// L=0: KI=132 CH=44 ; L=1: KI=256 CH=16.  inp: [64][KI]; Wl: [CH][128].
template<int L>
__device__ __forceinline__ void gate_body(
    float* __restrict__ inp, float* __restrict__ Wl,
    const float* __restrict__ Wg, const float* __restrict__ Wpre,
    const float* __restrict__ bgp, const float* __restrict__ E,
    const float* __restrict__ xsrc, const float* __restrict__ Axt,
    const float* __restrict__ h, const float* __restrict__ Ah,
    float* __restrict__ zh, float* __restrict__ rb, int t, int first,
    int n, int tid)
{
  constexpr int IX  = (L==0)?2:64;
  constexpr int KI  = 2*(IX+64);
  constexpr int CH  = (L==0)?44:16;
  constexpr int NCH = KI/CH;
  constexpr int O   = 128;

  for (int idx=tid; idx<64*IX; idx+=256){
    int bl = idx/IX, i = idx - bl*IX;
    inp[bl*KI + i] = (L==0)
      ? xsrc[(size_t)((bl*12+t)*1024+n)*2 + i]
      : xsrc[((size_t)bl<<16) + (size_t)n*64 + i];
  }
  for (int idx=tid; idx<4096; idx+=256){
    int bl = idx>>6, c = idx&63;
    inp[bl*KI + IX + c] = first ? 0.f : h[((size_t)bl<<16) + (size_t)n*64 + c];
  }
  for (int idx=tid; idx<64*IX; idx+=256){
    int bl = idx/IX, i = idx - bl*IX;
    inp[bl*KI + IX+64+i] = (L==0)
      ? Axt[(size_t)n*1536 + (size_t)(bl*12+t)*2 + i]
      : Axt[((size_t)bl<<16) + (size_t)n*64 + i];
  }
  for (int idx=tid; idx<4096; idx+=256){
    int bl = idx>>6, c = idx&63;
    inp[bl*KI + 2*IX+64+c] = first ? 0.f : Ah[((size_t)bl<<16) + (size_t)n*64 + c];
  }
  __syncthreads();

  int bg = tid >> 5;        // 8 groups of 8 batches
  int og = tid & 31;        // 32 groups of 4 outputs
  float acc[8][4];
#pragma unroll
  for (int d=0;d<4;++d){
    int o = og*4+d;
    float a = 0.f;
#pragma unroll
    for (int e=0;e<10;++e) a = fmaf(E[n*10+e], bgp[e*O+o], a);
#pragma unroll
    for (int bb=0;bb<8;++bb) acc[bb][d] = a;
  }

  for (int ch=0; ch<NCH; ++ch){
    if (Wpre){
      const float* src = Wpre + (size_t)n*(KI*O) + ch*CH*O;
      for (int idx=tid; idx<CH*O; idx+=256) Wl[idx] = src[idx];
    } else {
      for (int idx=tid; idx<CH*O; idx+=256){
        int i = idx>>7, o = idx&127;
        float a = 0.f;
#pragma unroll
        for (int e=0;e<10;++e)
          a = fmaf(E[n*10+e], Wg[((size_t)e*KI + ch*CH + i)*O + o], a);
        Wl[i*O + o] = a;
      }
    }
    __syncthreads();
    for (int i=0; i<CH; i+=4){
      float4 xq[8], wq[4];
#pragma unroll
      for (int bb=0;bb<8;++bb) xq[bb] = *(const float4*)&inp[(bg*8+bb)*KI + ch*CH + i];
#pragma unroll
      for (int ii=0;ii<4;++ii) wq[ii] = *(const float4*)&Wl[(i+ii)*O + og*4];
      float xv[8][4], wv[4][4];
#pragma unroll
      for (int bb=0;bb<8;++bb){ xv[bb][0]=xq[bb].x; xv[bb][1]=xq[bb].y; xv[bb][2]=xq[bb].z; xv[bb][3]=xq[bb].w; }
#pragma unroll
      for (int ii=0;ii<4;++ii){ wv[ii][0]=wq[ii].x; wv[ii][1]=wq[ii].y; wv[ii][2]=wq[ii].z; wv[ii][3]=wq[ii].w; }
#pragma unroll
      for (int bb=0;bb<8;++bb)
#pragma unroll
        for (int d=0;d<4;++d)
#pragma unroll
          for (int ii=0;ii<4;++ii)
            acc[bb][d] = fmaf(xv[bb][ii], wv[ii][d], acc[bb][d]);
    }
    __syncthreads();
  }

#pragma unroll
  for (int bb=0;bb<8;++bb){
    int b = bg*8 + bb;
    size_t base = ((size_t)b<<16) + (size_t)n*64;
#pragma unroll
    for (int d=0;d<4;++d){
      int o = og*4 + d;
      float s = 1.f/(1.f+__expf(-acc[bb][d]));
      if (o < 64){
        if (!first) zh[base+o] = s * h[base+o];
      } else {
        rb[base+o-64] = s;
      }
    }
  }
}

// ---------------------------------------------------------------------------
// Merged gate dispatch: y=0 -> layer l_y0; y=1 -> layer 0.  grid (1024, NL)
__global__ __launch_bounds__(256) void k_gateB(int l_y0,
    const float* __restrict__ Wg0, const float* __restrict__ Wg0p,
    const float* __restrict__ bg0,
    const float* __restrict__ Wg1, const float* __restrict__ Wg1p,
    const float* __restrict__ bg1,
    const float* __restrict__ E,  const float* __restrict__ x,
    const float* __restrict__ Ax0T,
    const float* __restrict__ h0cur, const float* __restrict__ h1,
    const float* __restrict__ Axt1,  const float* __restrict__ AhZ1,
    float* __restrict__ zh0, float* __restrict__ rb0,
    float* __restrict__ zh1, float* __restrict__ rb1,
    int t0, int first0, int first1)
{
  __shared__ float smem[18432];   // 73.7KB -> 2 blocks/CU
  int n = blockIdx.x, tid = threadIdx.x;
  int L = blockIdx.y ? 0 : l_y0;
  if (L == 1)
    gate_body<1>(smem, smem + 64*256, Wg1, Wg1p, bg1, E,
                 h0cur, Axt1, h1, AhZ1, zh1, rb1, 0, first1, n, tid);
  else
    gate_body<0>(smem, smem + 64*132, Wg0, Wg0p, bg0, E,
                 x, Ax0T, h0cur, Axt1, zh0, rb0, t0, first0, n, tid);
}

// ---------------------------------------------------------------------------
// Update body, 64 batches/block. L=0: KI=132 CH=44; L=1: KI=256 CH=32.
// L=1 accumulates q1acc[b,n,i] += <hn, V[i,tq,:]>.
template<int L>
__device__ __forceinline__ void upd_body(
    float* __restrict__ inp, float* __restrict__ Wl,
    const float* __restrict__ Wu, const float* __restrict__ Wpre,
    const float* __restrict__ bup, const float* __restrict__ E,
    const float* __restrict__ xsrc, const float* __restrict__ Axt,
    const float* __restrict__ zh, const float* __restrict__ Azh,
    const float* __restrict__ rb,
    const float* __restrict__ hread, float* __restrict__ hwrite,
    const float* __restrict__ V, float* __restrict__ q1acc,
    int t, int tq, int first, int n, int tid)
{
  constexpr int IX  = (L==0)?2:64;
  constexpr int KI  = 2*(IX+64);
  constexpr int CH  = (L==0)?44:32;
  constexpr int NCH = KI/CH;
  constexpr int O   = 64;

  for (int idx=tid; idx<64*IX; idx+=256){
    int bl = idx/IX, i = idx - bl*IX;
    inp[bl*KI + i] = (L==0)
      ? xsrc[(size_t)((bl*12+t)*1024+n)*2 + i]
      : xsrc[((size_t)bl<<16) + (size_t)n*64 + i];
  }
  for (int idx=tid; idx<4096; idx+=256){
    int bl = idx>>6, c = idx&63;
    inp[bl*KI + IX + c] = first ? 0.f : zh[((size_t)bl<<16) + (size_t)n*64 + c];
  }
  for (int idx=tid; idx<64*IX; idx+=256){
    int bl = idx/IX, i = idx - bl*IX;
    inp[bl*KI + IX+64+i] = (L==0)
      ? Axt[(size_t)n*1536 + (size_t)(bl*12+t)*2 + i]
      : Axt[((size_t)bl<<16) + (size_t)n*64 + i];
  }
  for (int idx=tid; idx<4096; idx+=256){
    int bl = idx>>6, c = idx&63;
    inp[bl*KI + 2*IX+64+c] = first ? 0.f : Azh[((size_t)bl<<16) + (size_t)n*64 + c];
  }
  __syncthreads();

  int bg = tid >> 5;        // 8 groups of 8 batches
  int og = tid & 31;        // 32 groups of 2 outputs
  float acc[8][2];
#pragma unroll
  for (int d=0;d<2;++d){
    int o = og*2+d;
    float a = 0.f;
#pragma unroll
    for (int e=0;e<10;++e) a = fmaf(E[n*10+e], bup[e*O+o], a);
#pragma unroll
    for (int bb=0;bb<8;++bb) acc[bb][d] = a;
  }

  for (int ch=0; ch<NCH; ++ch){
    if (Wpre){
      const float* src = Wpre + (size_t)n*(KI*O) + ch*CH*O;
      for (int idx=tid; idx<CH*O; idx+=256) Wl[idx] = src[idx];
    } else {
      for (int idx=tid; idx<CH*O; idx+=256){
        int i = idx>>6, o = idx&63;
        float a = 0.f;
#pragma unroll
        for (int e=0;e<10;++e)
          a = fmaf(E[n*10+e], Wu[((size_t)e*KI + ch*CH + i)*O + o], a);
        Wl[i*O + o] = a;
      }
    }
    __syncthreads();
    for (int i=0; i<CH; i+=4){
      float4 xq[8]; float2 wq[4];
#pragma unroll
      for (int bb=0;bb<8;++bb) xq[bb] = *(const float4*)&inp[(bg*8+bb)*KI + ch*CH + i];
#pragma unroll
      for (int ii=0;ii<4;++ii) wq[ii] = *(const float2*)&Wl[(i+ii)*O + og*2];
      float xv[8][4], wv[4][2];
#pragma unroll
      for (int bb=0;bb<8;++bb){ xv[bb][0]=xq[bb].x; xv[bb][1]=xq[bb].y; xv[bb][2]=xq[bb].z; xv[bb][3]=xq[bb].w; }
#pragma unroll
      for (int ii=0;ii<4;++ii){ wv[ii][0]=wq[ii].x; wv[ii][1]=wq[ii].y; }
#pragma unroll
      for (int bb=0;bb<8;++bb)
#pragma unroll
        for (int d=0;d<2;++d)
#pragma unroll
          for (int ii=0;ii<4;++ii)
            acc[bb][d] = fmaf(xv[bb][ii], wv[ii][d], acc[bb][d]);
    }
    __syncthreads();
  }

  float* hnL = inp;            // [64][65] overlay on inp (done with inp)
  float* VL  = inp + 4160;     // [12][64]
#pragma unroll
  for (int bb=0;bb<8;++bb){
    int b = bg*8 + bb;
    size_t base = ((size_t)b<<16) + (size_t)n*64;
#pragma unroll
    for (int d=0;d<2;++d){
      int o = og*2 + d;
      float hc = tanhf(acc[bb][d]);
      float r  = rb[base+o];
      float h0v = first ? 0.f : hread[base+o];
      float hn = r*h0v + (1.f-r)*hc;
      hwrite[base+o] = hn;
      if (L==1) hnL[b*65 + o] = hn;
    }
  }
  if (L==1){
    for (int idx=tid; idx<768; idx+=256)
      VL[idx] = V[((idx>>6)*12+tq)*64 + (idx&63)];
    __syncthreads();
    for (int task=tid; task<768; task+=256){
      int bl = task & 63, i = task >> 6;
      const float* hv = hnL + bl*65;
      const float* vv = VL + i*64;
      float s = 0.f;
#pragma unroll 8
      for (int c=0;c<64;++c) s = fmaf(hv[c], vv[c], s);
      size_t qi = (((size_t)bl<<10) + n)*12 + i;
      if (first) q1acc[qi] = s; else q1acc[qi] += s;
    }
  }
}

// ---------------------------------------------------------------------------
// Merged update dispatch: y=0 -> layer l_y0; y=1 -> layer 0.  grid (1024, NL)
__global__ __launch_bounds__(256) void k_updB(int l_y0,
    const float* __restrict__ Wu0, const float* __restrict__ Wu0p,
    const float* __restrict__ bu0,
    const float* __restrict__ Wu1, const float* __restrict__ Wu1p,
    const float* __restrict__ bu1,
    const float* __restrict__ E,  const float* __restrict__ x,
    const float* __restrict__ Ax0T, const float* __restrict__ Axt1,
    const float* __restrict__ h0cur, float* __restrict__ h0new,
    float* __restrict__ h1,
    const float* __restrict__ zh0, const float* __restrict__ Azh0,
    const float* __restrict__ rb0,
    const float* __restrict__ zh1, const float* __restrict__ Azh1,
    const float* __restrict__ rb1,
    const float* __restrict__ V, float* __restrict__ q1acc,
    int t0, int t1, int first0, int first1)
{
  __shared__ float smem[18432];
  int n = blockIdx.x, tid = threadIdx.x;
  int L = blockIdx.y ? 0 : l_y0;
  if (L == 1)
    upd_body<1>(smem, smem + 64*256, Wu1, Wu1p, bu1, E,
                h0cur, Axt1, zh1, Azh1, rb1, h1, h1, V, q1acc,
                0, t1, first1, n, tid);
  else
    upd_body<0>(smem, smem + 64*132, Wu0, Wu0p, bu0, E,
                x, Ax0T, zh0, Azh0, rb0, h0cur, h0new, nullptr, nullptr,
                t0, 0, first0, n, tid);
}

// ---------------------------------------------------------------------------
// q0buf[b,n,i] = sum_{ip,c} rel[b,ip,c]*(G[i,ip,2c]+dA*G[i,ip,2c+1])
__global__ __launch_bounds__(256) void k_q0G(
    const float* __restrict__ x, const float* __restrict__ diagA,
    const u16* __restrict__ G,
    const float* __restrict__ Wr, const float* __restrict__ br,
    float* __restrict__ q0buf)
{
  int n = blockIdx.x, tid = threadIdx.x;
  __shared__ u16  GL[18432];
  __shared__ float xsL[64][25];
  __shared__ float WrL[64][2];
  __shared__ float brL[64];

  for (int idx=tid; idx<18432; idx+=256) GL[idx] = G[idx];
  for (int idx=tid; idx<1536; idx+=256){
    int b = idx/24, r = idx - b*24;
    xsL[b][r] = x[(size_t)((b*12+(r>>1))*1024+n)*2 + (r&1)];
  }
  if (tid<128) WrL[tid>>1][tid&1] = Wr[tid];
  else if (tid<192) brL[tid-128] = br[tid-128];
  __syncthreads();

  float dA = diagA[n];
  int b = tid & 63, iq = tid >> 6;
  int i0 = iq*3;
  float q0a=0.f, q0b=0.f, q0c=0.f;
  for (int ip=0; ip<12; ++ip){
    float xa = xsL[b][ip*2], xb = xsL[b][ip*2+1];
    const u16* g0r = &GL[((i0+0)*12+ip)*128];
    const u16* g1r = &GL[((i0+1)*12+ip)*128];
    const u16* g2r = &GL[((i0+2)*12+ip)*128];
    for (int c=0;c<64;++c){
      float rel  = fmaf(xa, WrL[c][0], fmaf(xb, WrL[c][1], brL[c]));
      float relD = rel * dA;
      u32 g0 = *(const u32*)&g0r[2*c];
      u32 g1 = *(const u32*)&g1r[2*c];
      u32 g2 = *(const u32*)&g2r[2*c];
      q0a = fmaf(rel, bf2f((u16)g0), fmaf(relD, bf2f((u16)(g0>>16)), q0a));
      q0b = fmaf(rel, bf2f((u16)g1), fmaf(relD, bf2f((u16)(g1>>16)), q0b));
      q0c = fmaf(rel, bf2f((u16)g2), fmaf(relD, bf2f((u16)(g2>>16)), q0c));
    }
  }
  size_t qb = (((size_t)b<<10) + n)*12;
  q0buf[qb+i0]   = q0a;
  q0buf[qb+i0+1] = q0b;
  q0buf[qb+i0+2] = q0c;
}

// ---------------------------------------------------------------------------
// out[b,o,n] = b3eff[o] + sum_i q0*W3[o,i,0] + q1*W3[o,i,1]
__global__ __launch_bounds__(256) void k_head2(
    const float* __restrict__ q0buf, const float* __restrict__ q1acc,
    const float* __restrict__ W3, const float* __restrict__ b3eff,
    float* __restrict__ out)
{
  int n = blockIdx.x, tid = threadIdx.x;
  __shared__ float W3L[12][12][2];
  __shared__ float b3eL[12];
  __shared__ float q0L[64][12];
  __shared__ float q1L[64][12];

  if (tid < 12) b3eL[tid] = b3eff[tid];
  for (int idx=tid; idx<288; idx+=256){
    int o = idx/24, r = idx - o*24;
    W3L[o][r>>1][r&1] = W3[idx];
  }
  for (int idx=tid; idx<768; idx+=256){
    int b = idx/12, i = idx - (idx/12)*12;
    size_t base = (((size_t)b<<10) + n)*12 + i;
    q0L[b][i] = q0buf[base];
    q1L[b][i] = q1acc[base];
  }
  __syncthreads();

  for (int idx=tid; idx<768; idx+=256){
    int bb = idx/12, o = idx - (idx/12)*12;
    float a = b3eL[o];
#pragma unroll
    for (int i=0;i<12;++i)
      a += q0L[bb][i]*W3L[o][i][0] + q1L[bb][i]*W3L[o][i][1];
    out[(size_t)(bb*12+o)*1024 + n] = a;
  }
}

// ---------------------------------------------------------------------------
extern "C" void kernel_launch(void* const* d_in, const int* in_sizes, int n_in,
                              void* d_out, int out_size, void* d_ws, size_t ws_size,
                              hipStream_t stream)
{
  const float* x   = (const float*)d_in[0];
  const float* E   = (const float*)d_in[1];
  const float* Wg0 = (const float*)d_in[2];
  const float* bg0 = (const float*)d_in[3];
  const float* Wu0 = (const float*)d_in[4];
  const float* bu0 = (const float*)d_in[5];
  const float* Wg1 = (const float*)d_in[6];
  const float* bg1 = (const float*)d_in[7];
  const float* Wu1 = (const float*)d_in[8];
  const float* bu1 = (const float*)d_in[9];
  const float* Wr  = (const float*)d_in[10];
  const float* br  = (const float*)d_in[11];
  const float* W1  = (const float*)d_in[12];
  const float* Wc  = (const float*)d_in[13];
  const float* W2  = (const float*)d_in[14];
  const float* b2  = (const float*)d_in[15];
  const float* W3  = (const float*)d_in[16];
  const float* b3  = (const float*)d_in[17];

  char* ws = (char*)d_ws;
  size_t off = 0;
  auto alloc = [&](size_t bytes)->void*{
    void* p = ws + off; off += (bytes + 255) & ~(size_t)255; return p;
  };
  float* At    = (float*)alloc(1024ull*1024*4);
  float* diagA = (float*)alloc(1024*4);
  float* Ax0T  = (float*)alloc(1024ull*1536*4);
  float* Axt1  = (float*)alloc(64ull*65536*4);
  float* AhZ1  = (float*)alloc(64ull*65536*4);
  float* Azh0  = (float*)alloc(64ull*65536*4);
  float* Azh1  = (float*)alloc(64ull*65536*4);
  float* zh0   = (float*)alloc(64ull*65536*4);
  float* zh1   = (float*)alloc(64ull*65536*4);
  float* rb0   = (float*)alloc(64ull*65536*4);
  float* rb1   = (float*)alloc(64ull*65536*4);
  float* h0a   = (float*)alloc(64ull*65536*4);
  float* h0b   = (float*)alloc(64ull*65536*4);
  float* h1    = (float*)alloc(64ull*65536*4);
  float* q1acc = (float*)alloc(64ull*1024*12*4);
  float* q0buf = (float*)alloc(64ull*1024*12*4);
  float* V     = (float*)alloc(12ull*12*64*4);
  u16*   G     = (u16*)alloc(12ull*12*128*2);
  float* b3eff = (float*)alloc(12*4);

  if (off > ws_size) return;   // clean fail instead of fault

  // Precombined f32 weights — smallest-first to use the limited headroom.
  auto tryAlloc = [&](size_t bytes)->float*{
    size_t aligned = (bytes + 255) & ~(size_t)255;
    if (off + aligned > ws_size) return (float*)nullptr;
    void* p = ws + off; off += aligned; return (float*)p;
  };
  float* Wu0c = tryAlloc(1024ull*8448*4);
  float* Wu1c = tryAlloc(1024ull*16384*4);
  float* Wg0c = tryAlloc(1024ull*16896*4);
  float* Wg1c = tryAlloc(1024ull*32768*4);

  // ---- precomputes ----
  k_A2<<<dim3(1024),256,0,stream>>>(E, At, diagA);
  k_b3eff<<<dim3(1),64,0,stream>>>(b2, W3, b3, b3eff);
  k_Vpre<<<dim3(36),256,0,stream>>>(W1, W2, V);
  k_Gpre<<<dim3(72),256,0,stream>>>(Wc, W2, G);
  if (Wu0c) k_combF<<<dim3(1024, 33),256,0,stream>>>(Wu0, E, Wu0c,  8448);
  if (Wu1c) k_combF<<<dim3(1024, 64),256,0,stream>>>(Wu1, E, Wu1c, 16384);
  if (Wg0c) k_combF<<<dim3(1024, 66),256,0,stream>>>(Wg0, E, Wg0c, 16896);
  if (Wg1c) k_combF<<<dim3(1024,128),256,0,stream>>>(Wg1, E, Wg1c, 32768);
  gemm2x<<<dim3(16,24),256,0,stream>>>(At, x, Ax0T);
  k_q0G<<<dim3(1024),256,0,stream>>>(x, diagA, G, Wr, br, q0buf);

  // ---- pipeline prologue: layer0 @ t=0 ----
  k_gateB<<<dim3(1024,1),256,0,stream>>>(0, Wg0,Wg0c,bg0, Wg1,Wg1c,bg1,
      E, x, Ax0T, h0a, h1, Axt1, AhZ1, zh0, rb0, zh1, rb1, 0, 1, 0);
  k_updB<<<dim3(1024,1),256,0,stream>>>(0, Wu0,Wu0c,bu0, Wu1,Wu1c,bu1,
      E, x, Ax0T, Axt1, h0a, h0a, h1, zh0, Azh0, rb0, zh1, Azh1, rb1,
      V, q1acc, 0, 0, 1, 0);
  gemm9<<<dim3(8,32,1),256,0,stream>>>(At, h0a, Axt1, nullptr, nullptr);

  // ---- steady pipeline: iteration k = {layer1 @ t=k} || {layer0 @ t=k+1} ----
  for (int k=0; k<12; ++k){
    int last   = (k == 11);
    int first1 = (k == 0);
    float* h0cur = (k&1) ? h0b : h0a;
    float* h0new = (k&1) ? h0a : h0b;

    k_gateB<<<dim3(1024, last?1:2),256,0,stream>>>(1, Wg0,Wg0c,bg0,
        Wg1,Wg1c,bg1, E, x, Ax0T, h0cur, h1, Axt1, AhZ1,
        zh0, rb0, zh1, rb1, k+1, 0, first1);

    if (first1)
      gemm9<<<dim3(8,32,1),256,0,stream>>>(At, zh0, Azh0, nullptr, nullptr);
    else if (last)
      gemm9<<<dim3(8,32,1),256,0,stream>>>(At, zh1, Azh1, nullptr, nullptr);
    else
      gemm9<<<dim3(8,32,2),256,0,stream>>>(At, zh1, Azh1, zh0, Azh0);

    k_updB<<<dim3(1024, last?1:2),256,0,stream>>>(1, Wu0,Wu0c,bu0,
        Wu1,Wu1c,bu1, E, x, Ax0T, Axt1, h0cur, h0new, h1,
        zh0, Azh0, rb0, zh1, Azh1, rb1, V, q1acc, k+1, k, 0, first1);

    if (!last)
      gemm9<<<dim3(8,32,2),256,0,stream>>>(At, h1, AhZ1, h0new, Axt1);
  }

  // ---- output head ----
  k_head2<<<dim3(1024),256,0,stream>>>(q0buf, q1acc, W3, b3eff, (float*)d_out);
}

// Round 18
// 9279.548 us; speedup vs baseline: 1.2904x; 1.2904x over previous
//
#include <hip/hip_runtime.h>

typedef unsigned short u16;
typedef unsigned int   u32;

// B=64, T=12, N=1024, DIN=2, HID=64, ED=10, K=2
// f32 recurrence. Two-layer pipeline (layer1(t) || layer0(t+1)).
// R18: R16 structure (32-batch gate/upd, 2048 blocks) + float4 combine loads
// (4x fewer load instructions) + smallest-first precombine.

__device__ __forceinline__ float bf2f(u16 u){ return __uint_as_float(((u32)u)<<16); }
__device__ __forceinline__ u16 f2bf(float f){
  u32 u = __float_as_uint(f);
  return (u16)((u + 0x7fffu + ((u>>16)&1u)) >> 16);
}

// ---------------------------------------------------------------------------
// softmax(relu(E E^T), axis=1) -> col-major At, diagA.  grid 1024, block 256
__global__ __launch_bounds__(256) void k_A2(const float* __restrict__ E,
    float* __restrict__ At, float* __restrict__ diagA)
{
  __shared__ float EL[10][1024];
  __shared__ float row[1024];
  __shared__ float red[4];
  int n = blockIdx.x, tid = threadIdx.x;
  for (int idx=tid; idx<10240; idx+=256)
    EL[idx>>10][idx&1023] = E[(idx&1023)*10 + (idx>>10)];
  __syncthreads();
  float en[10];
#pragma unroll
  for (int e=0;e<10;++e) en[e] = EL[e][n];
  float lmax = -1e30f;
#pragma unroll
  for (int j=0;j<4;++j){
    int m = tid*4 + j;
    float d = 0.f;
#pragma unroll
    for (int e=0;e<10;++e) d = fmaf(en[e], EL[e][m], d);
    d = fmaxf(d, 0.f);
    row[m] = d; lmax = fmaxf(lmax, d);
  }
#pragma unroll
  for (int o=32;o>0;o>>=1) lmax = fmaxf(lmax, __shfl_xor(lmax, o));
  if ((tid&63)==0) red[tid>>6] = lmax;
  __syncthreads();
  float mx = fmaxf(fmaxf(red[0],red[1]), fmaxf(red[2],red[3]));
  __syncthreads();
  float lsum = 0.f;
#pragma unroll
  for (int j=0;j<4;++j){
    int m = tid*4 + j;
    float ex = expf(row[m] - mx);
    row[m] = ex; lsum += ex;
  }
#pragma unroll
  for (int o=32;o>0;o>>=1) lsum += __shfl_xor(lsum, o);
  if ((tid&63)==0) red[tid>>6] = lsum;
  __syncthreads();
  float inv = 1.f/(red[0]+red[1]+red[2]+red[3]);
#pragma unroll
  for (int j=0;j<4;++j){
    int m = tid*4 + j;
    float v = row[m]*inv;
    At[(size_t)m*1024 + n] = v;
    if (m == n) diagA[n] = v;
  }
}

// ---------------------------------------------------------------------------
__global__ __launch_bounds__(64) void k_b3eff(
    const float* __restrict__ b2, const float* __restrict__ W3,
    const float* __restrict__ b3, float* __restrict__ b3eff)
{
  int o = threadIdx.x;
  if (o < 12){
    float a = b3[o];
    for (int i=0;i<12;++i)
      a += b2[i] * (W3[(o*12+i)*2] + W3[(o*12+i)*2+1]);
    b3eff[o] = a;
  }
}

// ---------------------------------------------------------------------------
__global__ __launch_bounds__(256) void k_Vpre(const float* __restrict__ W1,
    const float* __restrict__ W2, float* __restrict__ V)
{
  int idx = blockIdx.x*256 + threadIdx.x;
  if (idx >= 9216) return;
  int c = idx & 63, r = idx >> 6;
  int j = r % 12, i = r / 12;
  float a = 0.f;
  for (int o=0;o<64;++o)
    a = fmaf(W2[(i*12+j)*64+o], W1[o*64+c], a);
  V[idx] = a;
}

// ---------------------------------------------------------------------------
__global__ __launch_bounds__(256) void k_Gpre(const float* __restrict__ Wc,
    const float* __restrict__ W2, u16* __restrict__ G)
{
  int idx = blockIdx.x*256 + threadIdx.x;
  int u = idx & 127, r = idx >> 7;
  int ip = r % 12, i = r / 12;
  float a = 0.f;
  int wlo = u>64 ? u-64 : 0;
  int whi = u<63 ? u : 63;
  for (int j=0;j<12;++j){
    const float* w2r = W2 + (i*12+j)*64;
    const float* wcr = Wc + (j*12+ip)*65;
    for (int w=wlo; w<=whi; ++w)
      a = fmaf(w2r[w], wcr[u-w], a);
  }
  G[idx] = f2bf(a);
}

// ---------------------------------------------------------------------------
__global__ __launch_bounds__(256) void k_combF(const float* __restrict__ Wp,
    const float* __restrict__ E, float* __restrict__ out, int plane)
{
  int n = blockIdx.x;
  int j = blockIdx.y*256 + threadIdx.x;
  if (j >= plane) return;
  float a = 0.f;
#pragma unroll
  for (int e=0;e<10;++e) a = fmaf(E[n*10+e], Wp[(size_t)e*plane + j], a);
  out[(size_t)n*plane + j] = a;
}

// ---------------------------------------------------------------------------
// gemm9: Y[s][n][c] = sum_m At[m][n]*X[s][m][c]  (f32)
// 128n x 128col tile (2 slabs/block), chunk 16, dbuf, 8x8 acc. XCD-sticky.
__global__ __launch_bounds__(256) void gemm9(const float* __restrict__ At,
    const float* __restrict__ X0, float* __restrict__ Y0,
    const float* __restrict__ X1, float* __restrict__ Y1)
{
  int flat = blockIdx.x + (blockIdx.y<<3) + (blockIdx.z<<8);
  int xt = flat & 7;
  int ys = (flat>>3) & 31;
  int zs = flat >> 8;
  const float* X = zs ? X1 : X0;
  float*       Y = zs ? Y1 : Y0;
  int n0 = xt * 128;
  long baseA = (long)(2*ys) * 65536;
  long baseB = baseA + 65536;
  __shared__ float Al[2][16*128];
  __shared__ float Xl[2][16*128];
  int tid = threadIdx.x;
  int tx = tid & 15, ty = tid >> 4;
  int ka = tid >> 5,  na = (tid & 31)*4;
  int cx = tid & 31;
  long xoff = (cx < 16) ? (baseA + (long)cx*4) : (baseB + (long)(cx-16)*4);

  float accA[8][4], accB[8][4];
#pragma unroll
  for (int r=0;r<8;++r)
#pragma unroll
    for (int c=0;c<4;++c){ accA[r][c]=0.f; accB[r][c]=0.f; }

  float4 ra0 = *(const float4*)(At + (size_t)ka*1024 + n0 + na);
  float4 ra1 = *(const float4*)(At + (size_t)(ka+8)*1024 + n0 + na);
  float4 rx0 = *(const float4*)(X + xoff + (long)ka*64);
  float4 rx1 = *(const float4*)(X + xoff + (long)(ka+8)*64);

  for (int m0=0; m0<1024; m0+=16){
    int cur = (m0>>4)&1;
    *(float4*)(Al[cur] + tid*4)       = ra0;
    *(float4*)(Al[cur] + (tid+256)*4) = ra1;
    *(float4*)(Xl[cur] + tid*4)       = rx0;
    *(float4*)(Xl[cur] + (tid+256)*4) = rx1;
    __syncthreads();
    if (m0+16 < 1024){
      int m1 = m0+16;
      ra0 = *(const float4*)(At + (size_t)(m1+ka)*1024 + n0 + na);
      ra1 = *(const float4*)(At + (size_t)(m1+ka+8)*1024 + n0 + na);
      rx0 = *(const float4*)(X + xoff + (long)(m1+ka)*64);
      rx1 = *(const float4*)(X + xoff + (long)(m1+ka+8)*64);
    }
#pragma unroll
    for (int kk=0;kk<16;++kk){
      float4 a0 = *(const float4*)(Al[cur] + kk*128 + ty*4);
      float4 a1 = *(const float4*)(Al[cur] + kk*128 + 64 + ty*4);
      float4 x0 = *(const float4*)(Xl[cur] + kk*128 + tx*4);
      float4 x1 = *(const float4*)(Xl[cur] + kk*128 + 64 + tx*4);
      float av[8] = {a0.x,a0.y,a0.z,a0.w,a1.x,a1.y,a1.z,a1.w};
      float xa[4] = {x0.x,x0.y,x0.z,x0.w};
      float xb[4] = {x1.x,x1.y,x1.z,x1.w};
#pragma unroll
      for (int r=0;r<8;++r)
#pragma unroll
        for (int c=0;c<4;++c){
          accA[r][c] = fmaf(av[r], xa[c], accA[r][c]);
          accB[r][c] = fmaf(av[r], xb[c], accB[r][c]);
        }
    }
  }
#pragma unroll
  for (int r=0;r<8;++r){
    int row = n0 + (r>>2)*64 + ty*4 + (r&3);
    float4 vA; vA.x=accA[r][0]; vA.y=accA[r][1]; vA.z=accA[r][2]; vA.w=accA[r][3];
    float4 vB; vB.x=accB[r][0]; vB.y=accB[r][1]; vB.z=accB[r][2]; vB.w=accB[r][3];
    *(float4*)&Y[baseA + (long)row*64 + tx*4] = vA;
    *(float4*)&Y[baseB + (long)row*64 + tx*4] = vB;
  }
}

// ---------------------------------------------------------------------------
// gemm2x (fused x-gather, one-shot): Ax0T[n][q] = sum_m At[m][n]*x[q>>1,m,q&1]
__global__ __launch_bounds__(256) void gemm2x(const float* __restrict__ At,
    const float* __restrict__ x, float* __restrict__ Y)
{
  __shared__ float Ats[64][65];
  __shared__ float Xs[64][65];
  int n0 = blockIdx.x*64;
  int q0 = blockIdx.y*64;
  int tid = threadIdx.x, c = tid & 63, rq = tid >> 6;
  float acc[16];
#pragma unroll
  for (int j=0;j<16;++j) acc[j]=0.f;
  for (int m0=0; m0<1024; m0+=64){
#pragma unroll
    for (int j=0;j<16;++j){
      int idx = tid + j*256;
      int k = idx>>6, r = idx&63;
      Ats[k][r] = At[(size_t)(m0+k)*1024 + n0 + r];
      int qg = q0 + r;
      Xs[k][r] = x[(size_t)(qg>>1)*2048 + (size_t)(m0+k)*2 + (qg&1)];
    }
    __syncthreads();
    for (int k=0;k<64;++k){
      float xv = Xs[k][c];
#pragma unroll
      for (int j=0;j<16;++j) acc[j] = fmaf(Ats[k][rq+4*j], xv, acc[j]);
    }
    __syncthreads();
  }
#pragma unroll
  for (int j=0;j<16;++j)
    Y[(size_t)(n0+rq+4*j)*1536 + q0 + c] = acc[j];
}

// ---------------------------------------------------------------------------
// Gate body (32 batches). float4 combine loads. Wpre -> float4 copy.
template<int L>
__device__ __forceinline__ void gate_body(
    float* __restrict__ inp, float* __restrict__ Wl,
    const float* __restrict__ Wg, const float* __restrict__ Wpre,
    const float* __restrict__ bgp, const float* __restrict__ E,
    const float* __restrict__ xsrc, const float* __restrict__ Axt,
    const float* __restrict__ h, const float* __restrict__ Ah,
    float* __restrict__ zh, float* __restrict__ rb, int t, int first,
    int n, int b0, int tid)
{
  constexpr int IX  = (L==0)?2:64;
  constexpr int KI  = 2*(IX+64);
  constexpr int CH  = (L==0)?44:32;
  constexpr int NCH = KI/CH;
  constexpr int O   = 128;

  for (int idx=tid; idx<32*IX; idx+=256){
    int bl = idx/IX, i = idx - bl*IX; int b = b0+bl;
    inp[bl*KI + i] = (L==0)
      ? xsrc[(size_t)((b*12+t)*1024+n)*2 + i]
      : xsrc[((size_t)b<<16) + (size_t)n*64 + i];
  }
  for (int idx=tid; idx<2048; idx+=256){
    int bl = idx>>6, c = idx&63; int b = b0+bl;
    inp[bl*KI + IX + c] = first ? 0.f : h[((size_t)b<<16) + (size_t)n*64 + c];
  }
  for (int idx=tid; idx<32*IX; idx+=256){
    int bl = idx/IX, i = idx - bl*IX; int b = b0+bl;
    inp[bl*KI + IX+64+i] = (L==0)
      ? Axt[(size_t)n*1536 + (size_t)(b*12+t)*2 + i]
      : Axt[((size_t)b<<16) + (size_t)n*64 + i];
  }
  for (int idx=tid; idx<2048; idx+=256){
    int bl = idx>>6, c = idx&63; int b = b0+bl;
    inp[bl*KI + 2*IX+64+c] = first ? 0.f : Ah[((size_t)b<<16) + (size_t)n*64 + c];
  }
  __syncthreads();

  int bg = tid >> 5;
  int og = tid & 31;
  float acc[4][4];
#pragma unroll
  for (int d=0;d<4;++d){
    int o = og*4+d;
    float a = 0.f;
#pragma unroll
    for (int e=0;e<10;++e) a = fmaf(E[n*10+e], bgp[e*O+o], a);
#pragma unroll
    for (int bl=0;bl<4;++bl) acc[bl][d] = a;
  }

  for (int ch=0; ch<NCH; ++ch){
    if (Wpre){
      const float4* src = (const float4*)(Wpre + (size_t)n*(KI*O) + ch*CH*O);
      for (int idx=tid; idx<CH*O/4; idx+=256) ((float4*)Wl)[idx] = src[idx];
    } else {
      for (int idx=tid; idx<CH*O/4; idx+=256){
        int i = idx>>5, o4 = idx&31;           // O/4 = 32
        float4 a; a.x=0.f; a.y=0.f; a.z=0.f; a.w=0.f;
#pragma unroll
        for (int e=0;e<10;++e){
          float w = E[n*10+e];
          float4 q = *(const float4*)(Wg + ((size_t)e*KI + ch*CH + i)*O + o4*4);
          a.x = fmaf(w,q.x,a.x); a.y = fmaf(w,q.y,a.y);
          a.z = fmaf(w,q.z,a.z); a.w = fmaf(w,q.w,a.w);
        }
        *(float4*)(Wl + i*O + o4*4) = a;
      }
    }
    __syncthreads();
    float4 xq[4], wq[4];
#pragma unroll
    for (int bl=0;bl<4;++bl) xq[bl] = *(const float4*)&inp[(bg*4+bl)*KI + ch*CH];
#pragma unroll
    for (int ii=0;ii<4;++ii) wq[ii] = *(const float4*)&Wl[ii*O + og*4];
    for (int i=0; i<CH; i+=4){
      int i2 = (i+4<CH) ? i+4 : i;
      float4 xq2[4], wq2[4];
#pragma unroll
      for (int bl=0;bl<4;++bl) xq2[bl] = *(const float4*)&inp[(bg*4+bl)*KI + ch*CH + i2];
#pragma unroll
      for (int ii=0;ii<4;++ii) wq2[ii] = *(const float4*)&Wl[(i2+ii)*O + og*4];
      float xv[4][4], wv[4][4];
#pragma unroll
      for (int bl=0;bl<4;++bl){ xv[bl][0]=xq[bl].x; xv[bl][1]=xq[bl].y; xv[bl][2]=xq[bl].z; xv[bl][3]=xq[bl].w; }
#pragma unroll
      for (int ii=0;ii<4;++ii){ wv[ii][0]=wq[ii].x; wv[ii][1]=wq[ii].y; wv[ii][2]=wq[ii].z; wv[ii][3]=wq[ii].w; }
#pragma unroll
      for (int bl=0;bl<4;++bl)
#pragma unroll
        for (int d=0;d<4;++d)
#pragma unroll
          for (int ii=0;ii<4;++ii)
            acc[bl][d] = fmaf(xv[bl][ii], wv[ii][d], acc[bl][d]);
#pragma unroll
      for (int bl=0;bl<4;++bl) xq[bl]=xq2[bl];
#pragma unroll
      for (int ii=0;ii<4;++ii) wq[ii]=wq2[ii];
    }
    __syncthreads();
  }

#pragma unroll
  for (int bl=0;bl<4;++bl){
    int b = b0 + bg*4 + bl;
    size_t base = ((size_t)b<<16) + (size_t)n*64;
#pragma unroll
    for (int d=0;d<4;++d){
      int o = og*4 + d;
      float s = 1.f/(1.f+__expf(-acc[bl][d]));
      if (o < 64){
        if (!first) zh[base+o] = s * h[base+o];
      } else {
        rb[base+o-64] = s;
      }
    }
  }
}

// ---------------------------------------------------------------------------
__global__ __launch_bounds__(256) void k_gateB(int l_z0,
    const float* __restrict__ Wg0, const float* __restrict__ Wg0p,
    const float* __restrict__ bg0,
    const float* __restrict__ Wg1, const float* __restrict__ Wg1p,
    const float* __restrict__ bg1,
    const float* __restrict__ E,  const float* __restrict__ x,
    const float* __restrict__ Ax0T,
    const float* __restrict__ h0cur, const float* __restrict__ h1,
    const float* __restrict__ Axt1,  const float* __restrict__ AhZ1,
    float* __restrict__ zh0, float* __restrict__ rb0,
    float* __restrict__ zh1, float* __restrict__ rb1,
    int t0, int first0, int first1)
{
  __shared__ float smem[12288];
  int n = blockIdx.x, b0 = blockIdx.y*32, tid = threadIdx.x;
  int L = blockIdx.z ? 0 : l_z0;
  if (L == 1)
    gate_body<1>(smem, smem + 32*256, Wg1, Wg1p, bg1, E,
                 h0cur, Axt1, h1, AhZ1, zh1, rb1, 0, first1, n, b0, tid);
  else
    gate_body<0>(smem, smem + 32*132, Wg0, Wg0p, bg0, E,
                 x, Ax0T, h0cur, Axt1, zh0, rb0, t0, first0, n, b0, tid);
}

// ---------------------------------------------------------------------------
// Update body (32 batches). float4 combine loads. L=1: fused q1 accumulation.
template<int L>
__device__ __forceinline__ void upd_body(
    float* __restrict__ inp, float* __restrict__ Wl,
    const float* __restrict__ Wu, const float* __restrict__ Wpre,
    const float* __restrict__ bup, const float* __restrict__ E,
    const float* __restrict__ xsrc, const float* __restrict__ Axt,
    const float* __restrict__ zh, const float* __restrict__ Azh,
    const float* __restrict__ rb,
    const float* __restrict__ hread, float* __restrict__ hwrite,
    const float* __restrict__ V, float* __restrict__ q1acc,
    int t, int tq, int first, int n, int b0, int tid)
{
  constexpr int IX  = (L==0)?2:64;
  constexpr int KI  = 2*(IX+64);
  constexpr int CH  = (L==0)?44:64;
  constexpr int NCH = KI/CH;
  constexpr int O   = 64;

  for (int idx=tid; idx<32*IX; idx+=256){
    int bl = idx/IX, i = idx - bl*IX; int b = b0+bl;
    inp[bl*KI + i] = (L==0)
      ? xsrc[(size_t)((b*12+t)*1024+n)*2 + i]
      : xsrc[((size_t)b<<16) + (size_t)n*64 + i];
  }
  for (int idx=tid; idx<2048; idx+=256){
    int bl = idx>>6, c = idx&63; int b = b0+bl;
    inp[bl*KI + IX + c] = first ? 0.f : zh[((size_t)b<<16) + (size_t)n*64 + c];
  }
  for (int idx=tid; idx<32*IX; idx+=256){
    int bl = idx/IX, i = idx - bl*IX; int b = b0+bl;
    inp[bl*KI + IX+64+i] = (L==0)
      ? Axt[(size_t)n*1536 + (size_t)(b*12+t)*2 + i]
      : Axt[((size_t)b<<16) + (size_t)n*64 + i];
  }
  for (int idx=tid; idx<2048; idx+=256){
    int bl = idx>>6, c = idx&63; int b = b0+bl;
    inp[bl*KI + 2*IX+64+c] = first ? 0.f : Azh[((size_t)b<<16) + (size_t)n*64 + c];
  }
  __syncthreads();

  int bg = tid >> 5;
  int og = tid & 31;
  float acc[4][2];
#pragma unroll
  for (int d=0;d<2;++d){
    int o = og*2+d;
    float a = 0.f;
#pragma unroll
    for (int e=0;e<10;++e) a = fmaf(E[n*10+e], bup[e*O+o], a);
#pragma unroll
    for (int bl=0;bl<4;++bl) acc[bl][d] = a;
  }

  for (int ch=0; ch<NCH; ++ch){
    if (Wpre){
      const float4* src = (const float4*)(Wpre + (size_t)n*(KI*O) + ch*CH*O);
      for (int idx=tid; idx<CH*O/4; idx+=256) ((float4*)Wl)[idx] = src[idx];
    } else {
      for (int idx=tid; idx<CH*O/4; idx+=256){
        int i = idx>>4, o4 = idx&15;           // O/4 = 16
        float4 a; a.x=0.f; a.y=0.f; a.z=0.f; a.w=0.f;
#pragma unroll
        for (int e=0;e<10;++e){
          float w = E[n*10+e];
          float4 q = *(const float4*)(Wu + ((size_t)e*KI + ch*CH + i)*O + o4*4);
          a.x = fmaf(w,q.x,a.x); a.y = fmaf(w,q.y,a.y);
          a.z = fmaf(w,q.z,a.z); a.w = fmaf(w,q.w,a.w);
        }
        *(float4*)(Wl + i*O + o4*4) = a;
      }
    }
    __syncthreads();
    float4 xq[4]; float2 wq[4];
#pragma unroll
    for (int bl=0;bl<4;++bl) xq[bl] = *(const float4*)&inp[(bg*4+bl)*KI + ch*CH];
#pragma unroll
    for (int ii=0;ii<4;++ii) wq[ii] = *(const float2*)&Wl[ii*O + og*2];
    for (int i=0; i<CH; i+=4){
      int i2 = (i+4<CH) ? i+4 : i;
      float4 xq2[4]; float2 wq2[4];
#pragma unroll
      for (int bl=0;bl<4;++bl) xq2[bl] = *(const float4*)&inp[(bg*4+bl)*KI + ch*CH + i2];
#pragma unroll
      for (int ii=0;ii<4;++ii) wq2[ii] = *(const float2*)&Wl[(i2+ii)*O + og*2];
      float xv[4][4], wv[4][2];
#pragma unroll
      for (int bl=0;bl<4;++bl){ xv[bl][0]=xq[bl].x; xv[bl][1]=xq[bl].y; xv[bl][2]=xq[bl].z; xv[bl][3]=xq[bl].w; }
#pragma unroll
      for (int ii=0;ii<4;++ii){ wv[ii][0]=wq[ii].x; wv[ii][1]=wq[ii].y; }
#pragma unroll
      for (int bl=0;bl<4;++bl)
#pragma unroll
        for (int d=0;d<2;++d)
#pragma unroll
          for (int ii=0;ii<4;++ii)
            acc[bl][d] = fmaf(xv[bl][ii], wv[ii][d], acc[bl][d]);
#pragma unroll
      for (int bl=0;bl<4;++bl) xq[bl]=xq2[bl];
#pragma unroll
      for (int ii=0;ii<4;++ii) wq[ii]=wq2[ii];
    }
    __syncthreads();
  }

  float* hnL = Wl;            // [32][65] overlay (L=1 only)
  float* VL  = Wl + 2080;     // [12][64]
#pragma unroll
  for (int bl=0;bl<4;++bl){
    int b = b0 + bg*4 + bl;
    size_t base = ((size_t)b<<16) + (size_t)n*64;
#pragma unroll
    for (int d=0;d<2;++d){
      int o = og*2 + d;
      float hc = tanhf(acc[bl][d]);
      float r  = rb[base+o];
      float h0v = first ? 0.f : hread[base+o];
      float hn = r*h0v + (1.f-r)*hc;
      hwrite[base+o] = hn;
      if (L==1) hnL[(bg*4+bl)*65 + o] = hn;
    }
  }
  if (L==1){
    for (int idx=tid; idx<768; idx+=256)
      VL[idx] = V[((idx>>6)*12+tq)*64 + (idx&63)];
    __syncthreads();
    for (int task=tid; task<384; task+=256){
      int bl = task & 31, i = task >> 5;
      const float* hv = hnL + bl*65;
      const float* vv = VL + i*64;
      float s = 0.f;
#pragma unroll 8
      for (int c=0;c<64;++c) s = fmaf(hv[c], vv[c], s);
      size_t qi = (((size_t)(b0+bl)<<10) + n)*12 + i;
      if (first) q1acc[qi] = s; else q1acc[qi] += s;
    }
  }
}

// ---------------------------------------------------------------------------
__global__ __launch_bounds__(256) void k_updB(int l_z0,
    const float* __restrict__ Wu0, const float* __restrict__ Wu0p,
    const float* __restrict__ bu0,
    const float* __restrict__ Wu1, const float* __restrict__ Wu1p,
    const float* __restrict__ bu1,
    const float* __restrict__ E,  const float* __restrict__ x,
    const float* __restrict__ Ax0T, const float* __restrict__ Axt1,
    const float* __restrict__ h0cur, float* __restrict__ h0new,
    float* __restrict__ h1,
    const float* __restrict__ zh0, const float* __restrict__ Azh0,
    const float* __restrict__ rb0,
    const float* __restrict__ zh1, const float* __restrict__ Azh1,
    const float* __restrict__ rb1,
    const float* __restrict__ V, float* __restrict__ q1acc,
    int t0, int t1, int first0, int first1)
{
  __shared__ float smem[12288];
  int n = blockIdx.x, b0 = blockIdx.y*32, tid = threadIdx.x;
  int L = blockIdx.z ? 0 : l_z0;
  if (L == 1)
    upd_body<1>(smem, smem + 32*256, Wu1, Wu1p, bu1, E,
                h0cur, Axt1, zh1, Azh1, rb1, h1, h1, V, q1acc,
                0, t1, first1, n, b0, tid);
  else
    upd_body<0>(smem, smem + 32*132, Wu0, Wu0p, bu0, E,
                x, Ax0T, zh0, Azh0, rb0, h0cur, h0new, nullptr, nullptr,
                t0, 0, first0, n, b0, tid);
}

// ---------------------------------------------------------------------------
// q0buf[b,n,i] = sum_{ip,c} rel[b,ip,c]*(G[i,ip,2c]+dA*G[i,ip,2c+1])
__global__ __launch_bounds__(256) void k_q0G(
    const float* __restrict__ x, const float* __restrict__ diagA,
    const u16* __restrict__ G,
    const float* __restrict__ Wr, const float* __restrict__ br,
    float* __restrict__ q0buf)
{
  int n = blockIdx.x, tid = threadIdx.x;
  __shared__ u16  GL[18432];
  __shared__ float xsL[64][25];
  __shared__ float WrL[64][2];
  __shared__ float brL[64];

  for (int idx=tid; idx<18432; idx+=256) GL[idx] = G[idx];
  for (int idx=tid; idx<1536; idx+=256){
    int b = idx/24, r = idx - b*24;
    xsL[b][r] = x[(size_t)((b*12+(r>>1))*1024+n)*2 + (r&1)];
  }
  if (tid<128) WrL[tid>>1][tid&1] = Wr[tid];
  else if (tid<192) brL[tid-128] = br[tid-128];
  __syncthreads();

  float dA = diagA[n];
  int b = tid & 63, iq = tid >> 6;
  int i0 = iq*3;
  float q0a=0.f, q0b=0.f, q0c=0.f;
  for (int ip=0; ip<12; ++ip){
    float xa = xsL[b][ip*2], xb = xsL[b][ip*2+1];
    const u16* g0r = &GL[((i0+0)*12+ip)*128];
    const u16* g1r = &GL[((i0+1)*12+ip)*128];
    const u16* g2r = &GL[((i0+2)*12+ip)*128];
    for (int c=0;c<64;++c){
      float rel  = fmaf(xa, WrL[c][0], fmaf(xb, WrL[c][1], brL[c]));
      float relD = rel * dA;
      u32 g0 = *(const u32*)&g0r[2*c];
      u32 g1 = *(const u32*)&g1r[2*c];
      u32 g2 = *(const u32*)&g2r[2*c];
      q0a = fmaf(rel, bf2f((u16)g0), fmaf(relD, bf2f((u16)(g0>>16)), q0a));
      q0b = fmaf(rel, bf2f((u16)g1), fmaf(relD, bf2f((u16)(g1>>16)), q0b));
      q0c = fmaf(rel, bf2f((u16)g2), fmaf(relD, bf2f((u16)(g2>>16)), q0c));
    }
  }
  size_t qb = (((size_t)b<<10) + n)*12;
  q0buf[qb+i0]   = q0a;
  q0buf[qb+i0+1] = q0b;
  q0buf[qb+i0+2] = q0c;
}

// ---------------------------------------------------------------------------
// out[b,o,n] = b3eff[o] + sum_i q0*W3[o,i,0] + q1*W3[o,i,1]
__global__ __launch_bounds__(256) void k_head2(
    const float* __restrict__ q0buf, const float* __restrict__ q1acc,
    const float* __restrict__ W3, const float* __restrict__ b3eff,
    float* __restrict__ out)
{
  int n = blockIdx.x, tid = threadIdx.x;
  __shared__ float W3L[12][12][2];
  __shared__ float b3eL[12];
  __shared__ float q0L[64][12];
  __shared__ float q1L[64][12];

  if (tid < 12) b3eL[tid] = b3eff[tid];
  for (int idx=tid; idx<288; idx+=256){
    int o = idx/24, r = idx - o*24;
    W3L[o][r>>1][r&1] = W3[idx];
  }
  for (int idx=tid; idx<768; idx+=256){
    int b = idx/12, i = idx - (idx/12)*12;
    size_t base = (((size_t)b<<10) + n)*12 + i;
    q0L[b][i] = q0buf[base];
    q1L[b][i] = q1acc[base];
  }
  __syncthreads();

  for (int idx=tid; idx<768; idx+=256){
    int bb = idx/12, o = idx - (idx/12)*12;
    float a = b3eL[o];
#pragma unroll
    for (int i=0;i<12;++i)
      a += q0L[bb][i]*W3L[o][i][0] + q1L[bb][i]*W3L[o][i][1];
    out[(size_t)(bb*12+o)*1024 + n] = a;
  }
}

// ---------------------------------------------------------------------------
extern "C" void kernel_launch(void* const* d_in, const int* in_sizes, int n_in,
                              void* d_out, int out_size, void* d_ws, size_t ws_size,
                              hipStream_t stream)
{
  const float* x   = (const float*)d_in[0];
  const float* E   = (const float*)d_in[1];
  const float* Wg0 = (const float*)d_in[2];
  const float* bg0 = (const float*)d_in[3];
  const float* Wu0 = (const float*)d_in[4];
  const float* bu0 = (const float*)d_in[5];
  const float* Wg1 = (const float*)d_in[6];
  const float* bg1 = (const float*)d_in[7];
  const float* Wu1 = (const float*)d_in[8];
  const float* bu1 = (const float*)d_in[9];
  const float* Wr  = (const float*)d_in[10];
  const float* br  = (const float*)d_in[11];
  const float* W1  = (const float*)d_in[12];
  const float* Wc  = (const float*)d_in[13];
  const float* W2  = (const float*)d_in[14];
  const float* b2  = (const float*)d_in[15];
  const float* W3  = (const float*)d_in[16];
  const float* b3  = (const float*)d_in[17];

  char* ws = (char*)d_ws;
  size_t off = 0;
  auto alloc = [&](size_t bytes)->void*{
    void* p = ws + off; off += (bytes + 255) & ~(size_t)255; return p;
  };
  float* At    = (float*)alloc(1024ull*1024*4);
  float* diagA = (float*)alloc(1024*4);
  float* Ax0T  = (float*)alloc(1024ull*1536*4);
  float* Axt1  = (float*)alloc(64ull*65536*4);
  float* AhZ1  = (float*)alloc(64ull*65536*4);
  float* Azh0  = (float*)alloc(64ull*65536*4);
  float* Azh1  = (float*)alloc(64ull*65536*4);
  float* zh0   = (float*)alloc(64ull*65536*4);
  float* zh1   = (float*)alloc(64ull*65536*4);
  float* rb0   = (float*)alloc(64ull*65536*4);
  float* rb1   = (float*)alloc(64ull*65536*4);
  float* h0a   = (float*)alloc(64ull*65536*4);
  float* h0b   = (float*)alloc(64ull*65536*4);
  float* h1    = (float*)alloc(64ull*65536*4);
  float* q1acc = (float*)alloc(64ull*1024*12*4);
  float* q0buf = (float*)alloc(64ull*1024*12*4);
  float* V     = (float*)alloc(12ull*12*64*4);
  u16*   G     = (u16*)alloc(12ull*12*128*2);
  float* b3eff = (float*)alloc(12*4);

  if (off > ws_size) return;   // clean fail instead of fault

  // Precombined f32 weights — smallest first (Wu0c likely fits).
  auto tryAlloc = [&](size_t bytes)->float*{
    size_t aligned = (bytes + 255) & ~(size_t)255;
    if (off + aligned > ws_size) return (float*)nullptr;
    void* p = ws + off; off += aligned; return (float*)p;
  };
  float* Wu0c = tryAlloc(1024ull*8448*4);
  float* Wu1c = tryAlloc(1024ull*16384*4);
  float* Wg0c = tryAlloc(1024ull*16896*4);
  float* Wg1c = tryAlloc(1024ull*32768*4);

  // ---- precomputes ----
  k_A2<<<dim3(1024),256,0,stream>>>(E, At, diagA);
  k_b3eff<<<dim3(1),64,0,stream>>>(b2, W3, b3, b3eff);
  k_Vpre<<<dim3(36),256,0,stream>>>(W1, W2, V);
  k_Gpre<<<dim3(72),256,0,stream>>>(Wc, W2, G);
  if (Wu0c) k_combF<<<dim3(1024, 33),256,0,stream>>>(Wu0, E, Wu0c,  8448);
  if (Wu1c) k_combF<<<dim3(1024, 64),256,0,stream>>>(Wu1, E, Wu1c, 16384);
  if (Wg0c) k_combF<<<dim3(1024, 66),256,0,stream>>>(Wg0, E, Wg0c, 16896);
  if (Wg1c) k_combF<<<dim3(1024,128),256,0,stream>>>(Wg1, E, Wg1c, 32768);
  gemm2x<<<dim3(16,24),256,0,stream>>>(At, x, Ax0T);
  k_q0G<<<dim3(1024),256,0,stream>>>(x, diagA, G, Wr, br, q0buf);

  // ---- pipeline prologue: layer0 @ t=0 ----
  k_gateB<<<dim3(1024,2,1),256,0,stream>>>(0, Wg0,Wg0c,bg0, Wg1,Wg1c,bg1,
      E, x, Ax0T, h0a, h1, Axt1, AhZ1, zh0, rb0, zh1, rb1, 0, 1, 0);
  k_updB<<<dim3(1024,2,1),256,0,stream>>>(0, Wu0,Wu0c,bu0, Wu1,Wu1c,bu1,
      E, x, Ax0T, Axt1, h0a, h0a, h1, zh0, Azh0, rb0, zh1, Azh1, rb1,
      V, q1acc, 0, 0, 1, 0);
  gemm9<<<dim3(8,32,1),256,0,stream>>>(At, h0a, Axt1, nullptr, nullptr);

  // ---- steady pipeline: iteration k = {layer1 @ t=k} || {layer0 @ t=k+1} ----
  for (int k=0; k<12; ++k){
    int last   = (k == 11);
    int first1 = (k == 0);
    float* h0cur = (k&1) ? h0b : h0a;
    float* h0new = (k&1) ? h0a : h0b;

    k_gateB<<<dim3(1024,2, last?1:2),256,0,stream>>>(1, Wg0,Wg0c,bg0,
        Wg1,Wg1c,bg1, E, x, Ax0T, h0cur, h1, Axt1, AhZ1,
        zh0, rb0, zh1, rb1, k+1, 0, first1);

    if (first1)
      gemm9<<<dim3(8,32,1),256,0,stream>>>(At, zh0, Azh0, nullptr, nullptr);
    else if (last)
      gemm9<<<dim3(8,32,1),256,0,stream>>>(At, zh1, Azh1, nullptr, nullptr);
    else
      gemm9<<<dim3(8,32,2),256,0,stream>>>(At, zh1, Azh1, zh0, Azh0);

    k_updB<<<dim3(1024,2, last?1:2),256,0,stream>>>(1, Wu0,Wu0c,bu0,
        Wu1,Wu1c,bu1, E, x, Ax0T, Axt1, h0cur, h0new, h1,
        zh0, Azh0, rb0, zh1, Azh1, rb1, V, q1acc, k+1, k, 0, first1);

    if (!last)
      gemm9<<<dim3(8,32,2),256,0,stream>>>(At, h1, AhZ1, h0new, Axt1);
  }

  // ---- output head ----
  k_head2<<<dim3(1024),256,0,stream>>>(q0buf, q1acc, W3, b3eff, (float*)d_out);
}

// Round 19
// 9123.713 us; speedup vs baseline: 1.3124x; 1.0171x over previous
//
#include <hip/hip_runtime.h>

typedef unsigned short u16;
typedef unsigned int   u32;

// B=64, T=12, N=1024, DIN=2, HID=64, ED=10, K=2
// f32 recurrence. Two-layer pipeline (layer1(t) || layer0(t+1)).
// R19: gate/upd LDS 48KB -> 40KB (4 blocks/CU): gateL1 CH=16, updL1 CH=32,
// q1 overlay moved to retired inp region. Bit-identical math.

__device__ __forceinline__ float bf2f(u16 u){ return __uint_as_float(((u32)u)<<16); }
__device__ __forceinline__ u16 f2bf(float f){
  u32 u = __float_as_uint(f);
  return (u16)((u + 0x7fffu + ((u>>16)&1u)) >> 16);
}

// ---------------------------------------------------------------------------
// softmax(relu(E E^T), axis=1) -> col-major At, diagA.  grid 1024, block 256
__global__ __launch_bounds__(256) void k_A2(const float* __restrict__ E,
    float* __restrict__ At, float* __restrict__ diagA)
{
  __shared__ float EL[10][1024];
  __shared__ float row[1024];
  __shared__ float red[4];
  int n = blockIdx.x, tid = threadIdx.x;
  for (int idx=tid; idx<10240; idx+=256)
    EL[idx>>10][idx&1023] = E[(idx&1023)*10 + (idx>>10)];
  __syncthreads();
  float en[10];
#pragma unroll
  for (int e=0;e<10;++e) en[e] = EL[e][n];
  float lmax = -1e30f;
#pragma unroll
  for (int j=0;j<4;++j){
    int m = tid*4 + j;
    float d = 0.f;
#pragma unroll
    for (int e=0;e<10;++e) d = fmaf(en[e], EL[e][m], d);
    d = fmaxf(d, 0.f);
    row[m] = d; lmax = fmaxf(lmax, d);
  }
#pragma unroll
  for (int o=32;o>0;o>>=1) lmax = fmaxf(lmax, __shfl_xor(lmax, o));
  if ((tid&63)==0) red[tid>>6] = lmax;
  __syncthreads();
  float mx = fmaxf(fmaxf(red[0],red[1]), fmaxf(red[2],red[3]));
  __syncthreads();
  float lsum = 0.f;
#pragma unroll
  for (int j=0;j<4;++j){
    int m = tid*4 + j;
    float ex = expf(row[m] - mx);
    row[m] = ex; lsum += ex;
  }
#pragma unroll
  for (int o=32;o>0;o>>=1) lsum += __shfl_xor(lsum, o);
  if ((tid&63)==0) red[tid>>6] = lsum;
  __syncthreads();
  float inv = 1.f/(red[0]+red[1]+red[2]+red[3]);
#pragma unroll
  for (int j=0;j<4;++j){
    int m = tid*4 + j;
    float v = row[m]*inv;
    At[(size_t)m*1024 + n] = v;
    if (m == n) diagA[n] = v;
  }
}

// ---------------------------------------------------------------------------
__global__ __launch_bounds__(64) void k_b3eff(
    const float* __restrict__ b2, const float* __restrict__ W3,
    const float* __restrict__ b3, float* __restrict__ b3eff)
{
  int o = threadIdx.x;
  if (o < 12){
    float a = b3[o];
    for (int i=0;i<12;++i)
      a += b2[i] * (W3[(o*12+i)*2] + W3[(o*12+i)*2+1]);
    b3eff[o] = a;
  }
}

// ---------------------------------------------------------------------------
__global__ __launch_bounds__(256) void k_Vpre(const float* __restrict__ W1,
    const float* __restrict__ W2, float* __restrict__ V)
{
  int idx = blockIdx.x*256 + threadIdx.x;
  if (idx >= 9216) return;
  int c = idx & 63, r = idx >> 6;
  int j = r % 12, i = r / 12;
  float a = 0.f;
  for (int o=0;o<64;++o)
    a = fmaf(W2[(i*12+j)*64+o], W1[o*64+c], a);
  V[idx] = a;
}

// ---------------------------------------------------------------------------
__global__ __launch_bounds__(256) void k_Gpre(const float* __restrict__ Wc,
    const float* __restrict__ W2, u16* __restrict__ G)
{
  int idx = blockIdx.x*256 + threadIdx.x;
  int u = idx & 127, r = idx >> 7;
  int ip = r % 12, i = r / 12;
  float a = 0.f;
  int wlo = u>64 ? u-64 : 0;
  int whi = u<63 ? u : 63;
  for (int j=0;j<12;++j){
    const float* w2r = W2 + (i*12+j)*64;
    const float* wcr = Wc + (j*12+ip)*65;
    for (int w=wlo; w<=whi; ++w)
      a = fmaf(w2r[w], wcr[u-w], a);
  }
  G[idx] = f2bf(a);
}

// ---------------------------------------------------------------------------
__global__ __launch_bounds__(256) void k_combF(const float* __restrict__ Wp,
    const float* __restrict__ E, float* __restrict__ out, int plane)
{
  int n = blockIdx.x;
  int j = blockIdx.y*256 + threadIdx.x;
  if (j >= plane) return;
  float a = 0.f;
#pragma unroll
  for (int e=0;e<10;++e) a = fmaf(E[n*10+e], Wp[(size_t)e*plane + j], a);
  out[(size_t)n*plane + j] = a;
}

// ---------------------------------------------------------------------------
// gemm9: Y[s][n][c] = sum_m At[m][n]*X[s][m][c]  (f32)
// 128n x 128col tile (2 slabs/block), chunk 16, dbuf, 8x8 acc. XCD-sticky.
__global__ __launch_bounds__(256) void gemm9(const float* __restrict__ At,
    const float* __restrict__ X0, float* __restrict__ Y0,
    const float* __restrict__ X1, float* __restrict__ Y1)
{
  int flat = blockIdx.x + (blockIdx.y<<3) + (blockIdx.z<<8);
  int xt = flat & 7;
  int ys = (flat>>3) & 31;
  int zs = flat >> 8;
  const float* X = zs ? X1 : X0;
  float*       Y = zs ? Y1 : Y0;
  int n0 = xt * 128;
  long baseA = (long)(2*ys) * 65536;
  long baseB = baseA + 65536;
  __shared__ float Al[2][16*128];
  __shared__ float Xl[2][16*128];
  int tid = threadIdx.x;
  int tx = tid & 15, ty = tid >> 4;
  int ka = tid >> 5,  na = (tid & 31)*4;
  int cx = tid & 31;
  long xoff = (cx < 16) ? (baseA + (long)cx*4) : (baseB + (long)(cx-16)*4);

  float accA[8][4], accB[8][4];
#pragma unroll
  for (int r=0;r<8;++r)
#pragma unroll
    for (int c=0;c<4;++c){ accA[r][c]=0.f; accB[r][c]=0.f; }

  float4 ra0 = *(const float4*)(At + (size_t)ka*1024 + n0 + na);
  float4 ra1 = *(const float4*)(At + (size_t)(ka+8)*1024 + n0 + na);
  float4 rx0 = *(const float4*)(X + xoff + (long)ka*64);
  float4 rx1 = *(const float4*)(X + xoff + (long)(ka+8)*64);

  for (int m0=0; m0<1024; m0+=16){
    int cur = (m0>>4)&1;
    *(float4*)(Al[cur] + tid*4)       = ra0;
    *(float4*)(Al[cur] + (tid+256)*4) = ra1;
    *(float4*)(Xl[cur] + tid*4)       = rx0;
    *(float4*)(Xl[cur] + (tid+256)*4) = rx1;
    __syncthreads();
    if (m0+16 < 1024){
      int m1 = m0+16;
      ra0 = *(const float4*)(At + (size_t)(m1+ka)*1024 + n0 + na);
      ra1 = *(const float4*)(At + (size_t)(m1+ka+8)*1024 + n0 + na);
      rx0 = *(const float4*)(X + xoff + (long)(m1+ka)*64);
      rx1 = *(const float4*)(X + xoff + (long)(m1+ka+8)*64);
    }
#pragma unroll
    for (int kk=0;kk<16;++kk){
      float4 a0 = *(const float4*)(Al[cur] + kk*128 + ty*4);
      float4 a1 = *(const float4*)(Al[cur] + kk*128 + 64 + ty*4);
      float4 x0 = *(const float4*)(Xl[cur] + kk*128 + tx*4);
      float4 x1 = *(const float4*)(Xl[cur] + kk*128 + 64 + tx*4);
      float av[8] = {a0.x,a0.y,a0.z,a0.w,a1.x,a1.y,a1.z,a1.w};
      float xa[4] = {x0.x,x0.y,x0.z,x0.w};
      float xb[4] = {x1.x,x1.y,x1.z,x1.w};
#pragma unroll
      for (int r=0;r<8;++r)
#pragma unroll
        for (int c=0;c<4;++c){
          accA[r][c] = fmaf(av[r], xa[c], accA[r][c]);
          accB[r][c] = fmaf(av[r], xb[c], accB[r][c]);
        }
    }
  }
#pragma unroll
  for (int r=0;r<8;++r){
    int row = n0 + (r>>2)*64 + ty*4 + (r&3);
    float4 vA; vA.x=accA[r][0]; vA.y=accA[r][1]; vA.z=accA[r][2]; vA.w=accA[r][3];
    float4 vB; vB.x=accB[r][0]; vB.y=accB[r][1]; vB.z=accB[r][2]; vB.w=accB[r][3];
    *(float4*)&Y[baseA + (long)row*64 + tx*4] = vA;
    *(float4*)&Y[baseB + (long)row*64 + tx*4] = vB;
  }
}

// ---------------------------------------------------------------------------
// gemm2x (fused x-gather, one-shot): Ax0T[n][q] = sum_m At[m][n]*x[q>>1,m,q&1]
__global__ __launch_bounds__(256) void gemm2x(const float* __restrict__ At,
    const float* __restrict__ x, float* __restrict__ Y)
{
  __shared__ float Ats[64][65];
  __shared__ float Xs[64][65];
  int n0 = blockIdx.x*64;
  int q0 = blockIdx.y*64;
  int tid = threadIdx.x, c = tid & 63, rq = tid >> 6;
  float acc[16];
#pragma unroll
  for (int j=0;j<16;++j) acc[j]=0.f;
  for (int m0=0; m0<1024; m0+=64){
#pragma unroll
    for (int j=0;j<16;++j){
      int idx = tid + j*256;
      int k = idx>>6, r = idx&63;
      Ats[k][r] = At[(size_t)(m0+k)*1024 + n0 + r];
      int qg = q0 + r;
      Xs[k][r] = x[(size_t)(qg>>1)*2048 + (size_t)(m0+k)*2 + (qg&1)];
    }
    __syncthreads();
    for (int k=0;k<64;++k){
      float xv = Xs[k][c];
#pragma unroll
      for (int j=0;j<16;++j) acc[j] = fmaf(Ats[k][rq+4*j], xv, acc[j]);
    }
    __syncthreads();
  }
#pragma unroll
  for (int j=0;j<16;++j)
    Y[(size_t)(n0+rq+4*j)*1536 + q0 + c] = acc[j];
}

// ---------------------------------------------------------------------------
// Gate body (32 batches). L=0: KI=132 CH=44; L=1: KI=256 CH=16 (40KB total).
template<int L>
__device__ __forceinline__ void gate_body(
    float* __restrict__ inp, float* __restrict__ Wl,
    const float* __restrict__ Wg, const float* __restrict__ Wpre,
    const float* __restrict__ bgp, const float* __restrict__ E,
    const float* __restrict__ xsrc, const float* __restrict__ Axt,
    const float* __restrict__ h, const float* __restrict__ Ah,
    float* __restrict__ zh, float* __restrict__ rb, int t, int first,
    int n, int b0, int tid)
{
  constexpr int IX  = (L==0)?2:64;
  constexpr int KI  = 2*(IX+64);
  constexpr int CH  = (L==0)?44:16;
  constexpr int NCH = KI/CH;
  constexpr int O   = 128;

  for (int idx=tid; idx<32*IX; idx+=256){
    int bl = idx/IX, i = idx - bl*IX; int b = b0+bl;
    inp[bl*KI + i] = (L==0)
      ? xsrc[(size_t)((b*12+t)*1024+n)*2 + i]
      : xsrc[((size_t)b<<16) + (size_t)n*64 + i];
  }
  for (int idx=tid; idx<2048; idx+=256){
    int bl = idx>>6, c = idx&63; int b = b0+bl;
    inp[bl*KI + IX + c] = first ? 0.f : h[((size_t)b<<16) + (size_t)n*64 + c];
  }
  for (int idx=tid; idx<32*IX; idx+=256){
    int bl = idx/IX, i = idx - bl*IX; int b = b0+bl;
    inp[bl*KI + IX+64+i] = (L==0)
      ? Axt[(size_t)n*1536 + (size_t)(b*12+t)*2 + i]
      : Axt[((size_t)b<<16) + (size_t)n*64 + i];
  }
  for (int idx=tid; idx<2048; idx+=256){
    int bl = idx>>6, c = idx&63; int b = b0+bl;
    inp[bl*KI + 2*IX+64+c] = first ? 0.f : Ah[((size_t)b<<16) + (size_t)n*64 + c];
  }
  __syncthreads();

  int bg = tid >> 5;
  int og = tid & 31;
  float acc[4][4];
#pragma unroll
  for (int d=0;d<4;++d){
    int o = og*4+d;
    float a = 0.f;
#pragma unroll
    for (int e=0;e<10;++e) a = fmaf(E[n*10+e], bgp[e*O+o], a);
#pragma unroll
    for (int bl=0;bl<4;++bl) acc[bl][d] = a;
  }

  for (int ch=0; ch<NCH; ++ch){
    if (Wpre){
      const float4* src = (const float4*)(Wpre + (size_t)n*(KI*O) + ch*CH*O);
      for (int idx=tid; idx<CH*O/4; idx+=256) ((float4*)Wl)[idx] = src[idx];
    } else {
      for (int idx=tid; idx<CH*O/4; idx+=256){
        int i = idx>>5, o4 = idx&31;           // O/4 = 32
        float4 a; a.x=0.f; a.y=0.f; a.z=0.f; a.w=0.f;
#pragma unroll
        for (int e=0;e<10;++e){
          float w = E[n*10+e];
          float4 q = *(const float4*)(Wg + ((size_t)e*KI + ch*CH + i)*O + o4*4);
          a.x = fmaf(w,q.x,a.x); a.y = fmaf(w,q.y,a.y);
          a.z = fmaf(w,q.z,a.z); a.w = fmaf(w,q.w,a.w);
        }
        *(float4*)(Wl + i*O + o4*4) = a;
      }
    }
    __syncthreads();
    float4 xq[4], wq[4];
#pragma unroll
    for (int bl=0;bl<4;++bl) xq[bl] = *(const float4*)&inp[(bg*4+bl)*KI + ch*CH];
#pragma unroll
    for (int ii=0;ii<4;++ii) wq[ii] = *(const float4*)&Wl[ii*O + og*4];
    for (int i=0; i<CH; i+=4){
      int i2 = (i+4<CH) ? i+4 : i;
      float4 xq2[4], wq2[4];
#pragma unroll
      for (int bl=0;bl<4;++bl) xq2[bl] = *(const float4*)&inp[(bg*4+bl)*KI + ch*CH + i2];
#pragma unroll
      for (int ii=0;ii<4;++ii) wq2[ii] = *(const float4*)&Wl[(i2+ii)*O + og*4];
      float xv[4][4], wv[4][4];
#pragma unroll
      for (int bl=0;bl<4;++bl){ xv[bl][0]=xq[bl].x; xv[bl][1]=xq[bl].y; xv[bl][2]=xq[bl].z; xv[bl][3]=xq[bl].w; }
#pragma unroll
      for (int ii=0;ii<4;++ii){ wv[ii][0]=wq[ii].x; wv[ii][1]=wq[ii].y; wv[ii][2]=wq[ii].z; wv[ii][3]=wq[ii].w; }
#pragma unroll
      for (int bl=0;bl<4;++bl)
#pragma unroll
        for (int d=0;d<4;++d)
#pragma unroll
          for (int ii=0;ii<4;++ii)
            acc[bl][d] = fmaf(xv[bl][ii], wv[ii][d], acc[bl][d]);
#pragma unroll
      for (int bl=0;bl<4;++bl) xq[bl]=xq2[bl];
#pragma unroll
      for (int ii=0;ii<4;++ii) wq[ii]=wq2[ii];
    }
    __syncthreads();
  }

#pragma unroll
  for (int bl=0;bl<4;++bl){
    int b = b0 + bg*4 + bl;
    size_t base = ((size_t)b<<16) + (size_t)n*64;
#pragma unroll
    for (int d=0;d<4;++d){
      int o = og*4 + d;
      float s = 1.f/(1.f+__expf(-acc[bl][d]));
      if (o < 64){
        if (!first) zh[base+o] = s * h[base+o];
      } else {
        rb[base+o-64] = s;
      }
    }
  }
}

// ---------------------------------------------------------------------------
__global__ __launch_bounds__(256) void k_gateB(int l_z0,
    const float* __restrict__ Wg0, const float* __restrict__ Wg0p,
    const float* __restrict__ bg0,
    const float* __restrict__ Wg1, const float* __restrict__ Wg1p,
    const float* __restrict__ bg1,
    const float* __restrict__ E,  const float* __restrict__ x,
    const float* __restrict__ Ax0T,
    const float* __restrict__ h0cur, const float* __restrict__ h1,
    const float* __restrict__ Axt1,  const float* __restrict__ AhZ1,
    float* __restrict__ zh0, float* __restrict__ rb0,
    float* __restrict__ zh1, float* __restrict__ rb1,
    int t0, int first0, int first1)
{
  __shared__ float smem[10240];   // 40KB -> 4 blocks/CU
  int n = blockIdx.x, b0 = blockIdx.y*32, tid = threadIdx.x;
  int L = blockIdx.z ? 0 : l_z0;
  if (L == 1)
    gate_body<1>(smem, smem + 32*256, Wg1, Wg1p, bg1, E,
                 h0cur, Axt1, h1, AhZ1, zh1, rb1, 0, first1, n, b0, tid);
  else
    gate_body<0>(smem, smem + 32*132, Wg0, Wg0p, bg0, E,
                 x, Ax0T, h0cur, Axt1, zh0, rb0, t0, first0, n, b0, tid);
}

// ---------------------------------------------------------------------------
// Update body (32 batches). L=0: KI=132 CH=44; L=1: KI=256 CH=32 (40KB).
// L=1 q1 overlay lives in retired inp region.
template<int L>
__device__ __forceinline__ void upd_body(
    float* __restrict__ inp, float* __restrict__ Wl,
    const float* __restrict__ Wu, const float* __restrict__ Wpre,
    const float* __restrict__ bup, const float* __restrict__ E,
    const float* __restrict__ xsrc, const float* __restrict__ Axt,
    const float* __restrict__ zh, const float* __restrict__ Azh,
    const float* __restrict__ rb,
    const float* __restrict__ hread, float* __restrict__ hwrite,
    const float* __restrict__ V, float* __restrict__ q1acc,
    int t, int tq, int first, int n, int b0, int tid)
{
  constexpr int IX  = (L==0)?2:64;
  constexpr int KI  = 2*(IX+64);
  constexpr int CH  = (L==0)?44:32;
  constexpr int NCH = KI/CH;
  constexpr int O   = 64;

  for (int idx=tid; idx<32*IX; idx+=256){
    int bl = idx/IX, i = idx - bl*IX; int b = b0+bl;
    inp[bl*KI + i] = (L==0)
      ? xsrc[(size_t)((b*12+t)*1024+n)*2 + i]
      : xsrc[((size_t)b<<16) + (size_t)n*64 + i];
  }
  for (int idx=tid; idx<2048; idx+=256){
    int bl = idx>>6, c = idx&63; int b = b0+bl;
    inp[bl*KI + IX + c] = first ? 0.f : zh[((size_t)b<<16) + (size_t)n*64 + c];
  }
  for (int idx=tid; idx<32*IX; idx+=256){
    int bl = idx/IX, i = idx - bl*IX; int b = b0+bl;
    inp[bl*KI + IX+64+i] = (L==0)
      ? Axt[(size_t)n*1536 + (size_t)(b*12+t)*2 + i]
      : Axt[((size_t)b<<16) + (size_t)n*64 + i];
  }
  for (int idx=tid; idx<2048; idx+=256){
    int bl = idx>>6, c = idx&63; int b = b0+bl;
    inp[bl*KI + 2*IX+64+c] = first ? 0.f : Azh[((size_t)b<<16) + (size_t)n*64 + c];
  }
  __syncthreads();

  int bg = tid >> 5;
  int og = tid & 31;
  float acc[4][2];
#pragma unroll
  for (int d=0;d<2;++d){
    int o = og*2+d;
    float a = 0.f;
#pragma unroll
    for (int e=0;e<10;++e) a = fmaf(E[n*10+e], bup[e*O+o], a);
#pragma unroll
    for (int bl=0;bl<4;++bl) acc[bl][d] = a;
  }

  for (int ch=0; ch<NCH; ++ch){
    if (Wpre){
      const float4* src = (const float4*)(Wpre + (size_t)n*(KI*O) + ch*CH*O);
      for (int idx=tid; idx<CH*O/4; idx+=256) ((float4*)Wl)[idx] = src[idx];
    } else {
      for (int idx=tid; idx<CH*O/4; idx+=256){
        int i = idx>>4, o4 = idx&15;           // O/4 = 16
        float4 a; a.x=0.f; a.y=0.f; a.z=0.f; a.w=0.f;
#pragma unroll
        for (int e=0;e<10;++e){
          float w = E[n*10+e];
          float4 q = *(const float4*)(Wu + ((size_t)e*KI + ch*CH + i)*O + o4*4);
          a.x = fmaf(w,q.x,a.x); a.y = fmaf(w,q.y,a.y);
          a.z = fmaf(w,q.z,a.z); a.w = fmaf(w,q.w,a.w);
        }
        *(float4*)(Wl + i*O + o4*4) = a;
      }
    }
    __syncthreads();
    float4 xq[4]; float2 wq[4];
#pragma unroll
    for (int bl=0;bl<4;++bl) xq[bl] = *(const float4*)&inp[(bg*4+bl)*KI + ch*CH];
#pragma unroll
    for (int ii=0;ii<4;++ii) wq[ii] = *(const float2*)&Wl[ii*O + og*2];
    for (int i=0; i<CH; i+=4){
      int i2 = (i+4<CH) ? i+4 : i;
      float4 xq2[4]; float2 wq2[4];
#pragma unroll
      for (int bl=0;bl<4;++bl) xq2[bl] = *(const float4*)&inp[(bg*4+bl)*KI + ch*CH + i2];
#pragma unroll
      for (int ii=0;ii<4;++ii) wq2[ii] = *(const float2*)&Wl[(i2+ii)*O + og*2];
      float xv[4][4], wv[4][2];
#pragma unroll
      for (int bl=0;bl<4;++bl){ xv[bl][0]=xq[bl].x; xv[bl][1]=xq[bl].y; xv[bl][2]=xq[bl].z; xv[bl][3]=xq[bl].w; }
#pragma unroll
      for (int ii=0;ii<4;++ii){ wv[ii][0]=wq[ii].x; wv[ii][1]=wq[ii].y; }
#pragma unroll
      for (int bl=0;bl<4;++bl)
#pragma unroll
        for (int d=0;d<2;++d)
#pragma unroll
          for (int ii=0;ii<4;++ii)
            acc[bl][d] = fmaf(xv[bl][ii], wv[ii][d], acc[bl][d]);
#pragma unroll
      for (int bl=0;bl<4;++bl) xq[bl]=xq2[bl];
#pragma unroll
      for (int ii=0;ii<4;++ii) wq[ii]=wq2[ii];
    }
    __syncthreads();
  }

  float* hnL = inp;            // [32][65] overlay in retired inp region
  float* VL  = inp + 2080;     // [12][64]
#pragma unroll
  for (int bl=0;bl<4;++bl){
    int b = b0 + bg*4 + bl;
    size_t base = ((size_t)b<<16) + (size_t)n*64;
#pragma unroll
    for (int d=0;d<2;++d){
      int o = og*2 + d;
      float hc = tanhf(acc[bl][d]);
      float r  = rb[base+o];
      float h0v = first ? 0.f : hread[base+o];
      float hn = r*h0v + (1.f-r)*hc;
      hwrite[base+o] = hn;
      if (L==1) hnL[(bg*4+bl)*65 + o] = hn;
    }
  }
  if (L==1){
    for (int idx=tid; idx<768; idx+=256)
      VL[idx] = V[((idx>>6)*12+tq)*64 + (idx&63)];
    __syncthreads();
    for (int task=tid; task<384; task+=256){
      int bl = task & 31, i = task >> 5;
      const float* hv = hnL + bl*65;
      const float* vv = VL + i*64;
      float s = 0.f;
#pragma unroll 8
      for (int c=0;c<64;++c) s = fmaf(hv[c], vv[c], s);
      size_t qi = (((size_t)(b0+bl)<<10) + n)*12 + i;
      if (first) q1acc[qi] = s; else q1acc[qi] += s;
    }
  }
}

// ---------------------------------------------------------------------------
__global__ __launch_bounds__(256) void k_updB(int l_z0,
    const float* __restrict__ Wu0, const float* __restrict__ Wu0p,
    const float* __restrict__ bu0,
    const float* __restrict__ Wu1, const float* __restrict__ Wu1p,
    const float* __restrict__ bu1,
    const float* __restrict__ E,  const float* __restrict__ x,
    const float* __restrict__ Ax0T, const float* __restrict__ Axt1,
    const float* __restrict__ h0cur, float* __restrict__ h0new,
    float* __restrict__ h1,
    const float* __restrict__ zh0, const float* __restrict__ Azh0,
    const float* __restrict__ rb0,
    const float* __restrict__ zh1, const float* __restrict__ Azh1,
    const float* __restrict__ rb1,
    const float* __restrict__ V, float* __restrict__ q1acc,
    int t0, int t1, int first0, int first1)
{
  __shared__ float smem[10240];   // 40KB -> 4 blocks/CU
  int n = blockIdx.x, b0 = blockIdx.y*32, tid = threadIdx.x;
  int L = blockIdx.z ? 0 : l_z0;
  if (L == 1)
    upd_body<1>(smem, smem + 32*256, Wu1, Wu1p, bu1, E,
                h0cur, Axt1, zh1, Azh1, rb1, h1, h1, V, q1acc,
                0, t1, first1, n, b0, tid);
  else
    upd_body<0>(smem, smem + 32*132, Wu0, Wu0p, bu0, E,
                x, Ax0T, zh0, Azh0, rb0, h0cur, h0new, nullptr, nullptr,
                t0, 0, first0, n, b0, tid);
}

// ---------------------------------------------------------------------------
// q0buf[b,n,i] = sum_{ip,c} rel[b,ip,c]*(G[i,ip,2c]+dA*G[i,ip,2c+1])
__global__ __launch_bounds__(256) void k_q0G(
    const float* __restrict__ x, const float* __restrict__ diagA,
    const u16* __restrict__ G,
    const float* __restrict__ Wr, const float* __restrict__ br,
    float* __restrict__ q0buf)
{
  int n = blockIdx.x, tid = threadIdx.x;
  __shared__ u16  GL[18432];
  __shared__ float xsL[64][25];
  __shared__ float WrL[64][2];
  __shared__ float brL[64];

  for (int idx=tid; idx<18432; idx+=256) GL[idx] = G[idx];
  for (int idx=tid; idx<1536; idx+=256){
    int b = idx/24, r = idx - b*24;
    xsL[b][r] = x[(size_t)((b*12+(r>>1))*1024+n)*2 + (r&1)];
  }
  if (tid<128) WrL[tid>>1][tid&1] = Wr[tid];
  else if (tid<192) brL[tid-128] = br[tid-128];
  __syncthreads();

  float dA = diagA[n];
  int b = tid & 63, iq = tid >> 6;
  int i0 = iq*3;
  float q0a=0.f, q0b=0.f, q0c=0.f;
  for (int ip=0; ip<12; ++ip){
    float xa = xsL[b][ip*2], xb = xsL[b][ip*2+1];
    const u16* g0r = &GL[((i0+0)*12+ip)*128];
    const u16* g1r = &GL[((i0+1)*12+ip)*128];
    const u16* g2r = &GL[((i0+2)*12+ip)*128];
    for (int c=0;c<64;++c){
      float rel  = fmaf(xa, WrL[c][0], fmaf(xb, WrL[c][1], brL[c]));
      float relD = rel * dA;
      u32 g0 = *(const u32*)&g0r[2*c];
      u32 g1 = *(const u32*)&g1r[2*c];
      u32 g2 = *(const u32*)&g2r[2*c];
      q0a = fmaf(rel, bf2f((u16)g0), fmaf(relD, bf2f((u16)(g0>>16)), q0a));
      q0b = fmaf(rel, bf2f((u16)g1), fmaf(relD, bf2f((u16)(g1>>16)), q0b));
      q0c = fmaf(rel, bf2f((u16)g2), fmaf(relD, bf2f((u16)(g2>>16)), q0c));
    }
  }
  size_t qb = (((size_t)b<<10) + n)*12;
  q0buf[qb+i0]   = q0a;
  q0buf[qb+i0+1] = q0b;
  q0buf[qb+i0+2] = q0c;
}

// ---------------------------------------------------------------------------
// out[b,o,n] = b3eff[o] + sum_i q0*W3[o,i,0] + q1*W3[o,i,1]
__global__ __launch_bounds__(256) void k_head2(
    const float* __restrict__ q0buf, const float* __restrict__ q1acc,
    const float* __restrict__ W3, const float* __restrict__ b3eff,
    float* __restrict__ out)
{
  int n = blockIdx.x, tid = threadIdx.x;
  __shared__ float W3L[12][12][2];
  __shared__ float b3eL[12];
  __shared__ float q0L[64][12];
  __shared__ float q1L[64][12];

  if (tid < 12) b3eL[tid] = b3eff[tid];
  for (int idx=tid; idx<288; idx+=256){
    int o = idx/24, r = idx - o*24;
    W3L[o][r>>1][r&1] = W3[idx];
  }
  for (int idx=tid; idx<768; idx+=256){
    int b = idx/12, i = idx - (idx/12)*12;
    size_t base = (((size_t)b<<10) + n)*12 + i;
    q0L[b][i] = q0buf[base];
    q1L[b][i] = q1acc[base];
  }
  __syncthreads();

  for (int idx=tid; idx<768; idx+=256){
    int bb = idx/12, o = idx - (idx/12)*12;
    float a = b3eL[o];
#pragma unroll
    for (int i=0;i<12;++i)
      a += q0L[bb][i]*W3L[o][i][0] + q1L[bb][i]*W3L[o][i][1];
    out[(size_t)(bb*12+o)*1024 + n] = a;
  }
}

// ---------------------------------------------------------------------------
extern "C" void kernel_launch(void* const* d_in, const int* in_sizes, int n_in,
                              void* d_out, int out_size, void* d_ws, size_t ws_size,
                              hipStream_t stream)
{
  const float* x   = (const float*)d_in[0];
  const float* E   = (const float*)d_in[1];
  const float* Wg0 = (const float*)d_in[2];
  const float* bg0 = (const float*)d_in[3];
  const float* Wu0 = (const float*)d_in[4];
  const float* bu0 = (const float*)d_in[5];
  const float* Wg1 = (const float*)d_in[6];
  const float* bg1 = (const float*)d_in[7];
  const float* Wu1 = (const float*)d_in[8];
  const float* bu1 = (const float*)d_in[9];
  const float* Wr  = (const float*)d_in[10];
  const float* br  = (const float*)d_in[11];
  const float* W1  = (const float*)d_in[12];
  const float* Wc  = (const float*)d_in[13];
  const float* W2  = (const float*)d_in[14];
  const float* b2  = (const float*)d_in[15];
  const float* W3  = (const float*)d_in[16];
  const float* b3  = (const float*)d_in[17];

  char* ws = (char*)d_ws;
  size_t off = 0;
  auto alloc = [&](size_t bytes)->void*{
    void* p = ws + off; off += (bytes + 255) & ~(size_t)255; return p;
  };
  float* At    = (float*)alloc(1024ull*1024*4);
  float* diagA = (float*)alloc(1024*4);
  float* Ax0T  = (float*)alloc(1024ull*1536*4);
  float* Axt1  = (float*)alloc(64ull*65536*4);
  float* AhZ1  = (float*)alloc(64ull*65536*4);
  float* Azh0  = (float*)alloc(64ull*65536*4);
  float* Azh1  = (float*)alloc(64ull*65536*4);
  float* zh0   = (float*)alloc(64ull*65536*4);
  float* zh1   = (float*)alloc(64ull*65536*4);
  float* rb0   = (float*)alloc(64ull*65536*4);
  float* rb1   = (float*)alloc(64ull*65536*4);
  float* h0a   = (float*)alloc(64ull*65536*4);
  float* h0b   = (float*)alloc(64ull*65536*4);
  float* h1    = (float*)alloc(64ull*65536*4);
  float* q1acc = (float*)alloc(64ull*1024*12*4);
  float* q0buf = (float*)alloc(64ull*1024*12*4);
  float* V     = (float*)alloc(12ull*12*64*4);
  u16*   G     = (u16*)alloc(12ull*12*128*2);
  float* b3eff = (float*)alloc(12*4);

  if (off > ws_size) return;   // clean fail instead of fault

  // Precombined f32 weights — smallest first.
  auto tryAlloc = [&](size_t bytes)->float*{
    size_t aligned = (bytes + 255) & ~(size_t)255;
    if (off + aligned > ws_size) return (float*)nullptr;
    void* p = ws + off; off += aligned; return (float*)p;
  };
  float* Wu0c = tryAlloc(1024ull*8448*4);
  float* Wu1c = tryAlloc(1024ull*16384*4);
  float* Wg0c = tryAlloc(1024ull*16896*4);
  float* Wg1c = tryAlloc(1024ull*32768*4);

  // ---- precomputes ----
  k_A2<<<dim3(1024),256,0,stream>>>(E, At, diagA);
  k_b3eff<<<dim3(1),64,0,stream>>>(b2, W3, b3, b3eff);
  k_Vpre<<<dim3(36),256,0,stream>>>(W1, W2, V);
  k_Gpre<<<dim3(72),256,0,stream>>>(Wc, W2, G);
  if (Wu0c) k_combF<<<dim3(1024, 33),256,0,stream>>>(Wu0, E, Wu0c,  8448);
  if (Wu1c) k_combF<<<dim3(1024, 64),256,0,stream>>>(Wu1, E, Wu1c, 16384);
  if (Wg0c) k_combF<<<dim3(1024, 66),256,0,stream>>>(Wg0, E, Wg0c, 16896);
  if (Wg1c) k_combF<<<dim3(1024,128),256,0,stream>>>(Wg1, E, Wg1c, 32768);
  gemm2x<<<dim3(16,24),256,0,stream>>>(At, x, Ax0T);
  k_q0G<<<dim3(1024),256,0,stream>>>(x, diagA, G, Wr, br, q0buf);

  // ---- pipeline prologue: layer0 @ t=0 ----
  k_gateB<<<dim3(1024,2,1),256,0,stream>>>(0, Wg0,Wg0c,bg0, Wg1,Wg1c,bg1,
      E, x, Ax0T, h0a, h1, Axt1, AhZ1, zh0, rb0, zh1, rb1, 0, 1, 0);
  k_updB<<<dim3(1024,2,1),256,0,stream>>>(0, Wu0,Wu0c,bu0, Wu1,Wu1c,bu1,
      E, x, Ax0T, Axt1, h0a, h0a, h1, zh0, Azh0, rb0, zh1, Azh1, rb1,
      V, q1acc, 0, 0, 1, 0);
  gemm9<<<dim3(8,32,1),256,0,stream>>>(At, h0a, Axt1, nullptr, nullptr);

  // ---- steady pipeline: iteration k = {layer1 @ t=k} || {layer0 @ t=k+1} ----
  for (int k=0; k<12; ++k){
    int last   = (k == 11);
    int first1 = (k == 0);
    float* h0cur = (k&1) ? h0b : h0a;
    float* h0new = (k&1) ? h0a : h0b;

    k_gateB<<<dim3(1024,2, last?1:2),256,0,stream>>>(1, Wg0,Wg0c,bg0,
        Wg1,Wg1c,bg1, E, x, Ax0T, h0cur, h1, Axt1, AhZ1,
        zh0, rb0, zh1, rb1, k+1, 0, first1);

    if (first1)
      gemm9<<<dim3(8,32,1),256,0,stream>>>(At, zh0, Azh0, nullptr, nullptr);
    else if (last)
      gemm9<<<dim3(8,32,1),256,0,stream>>>(At, zh1, Azh1, nullptr, nullptr);
    else
      gemm9<<<dim3(8,32,2),256,0,stream>>>(At, zh1, Azh1, zh0, Azh0);

    k_updB<<<dim3(1024,2, last?1:2),256,0,stream>>>(1, Wu0,Wu0c,bu0,
        Wu1,Wu1c,bu1, E, x, Ax0T, Axt1, h0cur, h0new, h1,
        zh0, Azh0, rb0, zh1, Azh1, rb1, V, q1acc, k+1, k, 0, first1);

    if (!last)
      gemm9<<<dim3(8,32,2),256,0,stream>>>(At, h1, AhZ1, h0new, Axt1);
  }

  // ---- output head ----
  k_head2<<<dim3(1024),256,0,stream>>>(q0buf, q1acc, W3, b3eff, (float*)d_out);
}